// Round 8
// baseline (616.457 us; speedup 1.0000x reference)
//
#include <hip/hip_runtime.h>
#include <hip/hip_bf16.h>
#include <cstdint>
#include <cstddef>

#define NNODES 100000
#define NEDGES 1600000
#define NCLS 40
#define NBLK_SCAN 391   // ceil(100000/256)
#define NBUCK 391       // dst>>8 buckets (256 nodes each)
#define BCAP 5120       // bucket capacity (mean 4096, +16 sigma)
#define NBLKB 256
#define CHUNK 6250      // NEDGES / NBLKB exactly
#define MPAD 100096     // 782*128, zero-padded rows

typedef _Float16 f16;
typedef _Float16 f16x8 __attribute__((ext_vector_type(8)));
typedef float f32x4 __attribute__((ext_vector_type(4)));

__device__ inline float h2f(unsigned short u) {
    f16 h; __builtin_memcpy(&h, &u, 2); return (float)h;
}
__device__ inline unsigned short f2h(float f) {
    f16 h = (f16)f; unsigned short u; __builtin_memcpy(&u, &h, 2); return u;
}
__device__ inline void gload_lds16(const void* g, void* l) {
    __builtin_amdgcn_global_load_lds((const __attribute__((address_space(1))) unsigned int*)g,
                                     (__attribute__((address_space(3))) unsigned int*)l, 16, 0, 0);
}
// a_lo += (float)f16_lo(u); a_hi += (float)f16_hi(u)  — one v_fma_mix_f32 each (bit-exact cvt+fp32 add)
__device__ inline void fmix2(float& alo, float& ahi, unsigned u, float one) {
    asm("v_fma_mix_f32 %0, %1, %2, %0 op_sel:[0,0,0] op_sel_hi:[1,0,0]"
        : "+v"(alo) : "v"(u), "v"(one));
    asm("v_fma_mix_f32 %0, %1, %2, %0 op_sel:[1,0,0] op_sel_hi:[1,0,0]"
        : "+v"(ahi) : "v"(u), "v"(one));
}

// ---------------- edge dtype detect ----------------
__global__ void k_detect(const int* __restrict__ ei, int* __restrict__ flag) {
    if (threadIdx.x == 0 && blockIdx.x == 0) {
        int nz = 0;
        for (int i = 1; i < 256; i += 2) nz |= ei[i];
        *flag = (nz == 0) ? 1 : 0;   // 1 => int64 layout
    }
}

// ---------------- bucketed edge partition (LDS histogram + grouped writes) ----------------
__global__ __launch_bounds__(256) void k_bucket(const int* __restrict__ ei,
        const int* __restrict__ flag, int* __restrict__ gbcnt, int2* __restrict__ bedge) {
    __shared__ int lcnt[NBUCK], lbase[NBUCK], lcur[NBUCK];
    const int t = threadIdx.x;
    const int is64 = *flag;
    for (int i = t; i < NBUCK; i += 256) lcnt[i] = 0;
    __syncthreads();
    const int e0 = blockIdx.x * CHUNK;
    for (int i = t; i < CHUNK; i += 256) {
        int e = e0 + i;
        int d = is64 ? ei[2 * ((size_t)NEDGES + e)] : ei[NEDGES + e];
        atomicAdd(&lcnt[d >> 8], 1);
    }
    __syncthreads();
    for (int i = t; i < NBUCK; i += 256) {
        int c = lcnt[i];
        lbase[i] = c ? atomicAdd(&gbcnt[i], c) : 0;
        lcur[i] = 0;
    }
    __syncthreads();
    for (int i = t; i < CHUNK; i += 256) {
        int e = e0 + i;
        int s, d;
        if (is64) { s = ei[2 * (size_t)e]; d = ei[2 * ((size_t)NEDGES + e)]; }
        else      { s = ei[e];             d = ei[NEDGES + e]; }
        int b = d >> 8;
        int p = lbase[b] + atomicAdd(&lcur[b], 1);
        if (p < BCAP) bedge[(size_t)b * BCAP + p] = make_int2(s, d);
    }
}

// ---------------- per-bucket node-degree count ----------------
__global__ __launch_bounds__(256) void k_cnt(const int* __restrict__ gbcnt,
        const int2* __restrict__ bedge, int* __restrict__ cnt) {
    __shared__ int lc[256];
    const int t = threadIdx.x, b = blockIdx.x;
    lc[t] = 0;
    __syncthreads();
    const int ne = min(gbcnt[b], BCAP);
    const int2* be = bedge + (size_t)b * BCAP;
    for (int i = t; i < ne; i += 256)
        atomicAdd(&lc[be[i].y & 255], 1);
    __syncthreads();
    int node = b * 256 + t;
    if (node < NNODES) cnt[node] = lc[t];
}

// dinv over MPAD (pad rows -> 0)
__global__ __launch_bounds__(256) void k_dinv(const int* __restrict__ cnt, float* __restrict__ dinv) {
    int i = blockIdx.x * 256 + threadIdx.x;
    if (i < MPAD) dinv[i] = (i < NNODES) ? rsqrtf((float)(cnt[i] + 1)) : 0.f;
}

// ---------------- hierarchical scan over (cnt[i]+1)  (self-loop included) ----------------
__global__ __launch_bounds__(256) void k_scan1(const int* __restrict__ cnt,
        int* __restrict__ incl, int* __restrict__ blksum) {
    __shared__ int sm[256];
    const int t = threadIdx.x;
    int i = blockIdx.x * 256 + t;
    int v = (i < NNODES) ? (cnt[i] + 1) : 0;
    sm[t] = v;
    __syncthreads();
    for (int d = 1; d < 256; d <<= 1) {
        int x = (t >= d) ? sm[t - d] : 0;
        __syncthreads();
        sm[t] += x;
        __syncthreads();
    }
    if (i < NNODES) incl[i] = sm[t];
    if (t == 255) blksum[blockIdx.x] = sm[255];
}

__global__ __launch_bounds__(512) void k_scan2(const int* __restrict__ blksum, int* __restrict__ blkoff) {
    __shared__ int sm[512];
    const int t = threadIdx.x;
    int v = (t < NBLK_SCAN) ? blksum[t] : 0;
    sm[t] = v;
    __syncthreads();
    for (int d = 1; d < 512; d <<= 1) {
        int x = (t >= d) ? sm[t - d] : 0;
        __syncthreads();
        sm[t] += x;
        __syncthreads();
    }
    if (t < NBLK_SCAN) blkoff[t] = sm[t] - v;
}

__global__ __launch_bounds__(256) void k_scan3(const int* __restrict__ incl,
        const int* __restrict__ blkoff, int* __restrict__ offs) {
    int i = blockIdx.x * 256 + threadIdx.x;
    if (i < NNODES) offs[i + 1] = incl[i] + blkoff[blockIdx.x];
    if (i == 0) offs[0] = 0;
}

// self edge at slot 0 of each node's bucket
__global__ __launch_bounds__(256) void k_self(const int* __restrict__ offs, int* __restrict__ esrc) {
    int i = blockIdx.x * 256 + threadIdx.x;
    if (i < NNODES) esrc[offs[i]] = i;
}

// ---------------- per-bucket exact scatter (L2-local, block-exclusive region) ----------------
__global__ __launch_bounds__(256) void k_fill2(const int* __restrict__ gbcnt,
        const int2* __restrict__ bedge, const int* __restrict__ offs, int* __restrict__ esrc) {
    __shared__ int loff[256], lcur[256];
    const int t = threadIdx.x, b = blockIdx.x;
    int node = b * 256 + t;
    loff[t] = (node < NNODES) ? offs[node] : 0;
    lcur[t] = 0;
    __syncthreads();
    const int ne = min(gbcnt[b], BCAP);
    const int2* be = bedge + (size_t)b * BCAP;
    for (int i = t; i < ne; i += 256) {
        int2 sd = be[i];
        int li = sd.y & 255;
        int p = loff[li] + 1 + atomicAdd(&lcur[li], 1);   // +1: slot 0 is self-loop
        esrc[p] = sd.x;
    }
}

// ---------------- W[256][256] fp32 -> WT[n][k] fp16 ----------------
__global__ __launch_bounds__(256) void k_wt(const float* __restrict__ W, unsigned short* __restrict__ WT) {
    int k = blockIdx.x;
    int n = threadIdx.x;
    WT[n * 256 + k] = f2h(W[k * 256 + n]);
}

// W3[256][40] fp32 -> W3T[128][256] fp16 (rows 40..127 zero)
__global__ __launch_bounds__(256) void k_wt3(const float* __restrict__ W, unsigned short* __restrict__ WT) {
    int n = blockIdx.x;    // 0..127
    int k = threadIdx.x;   // 0..255
    WT[n * 256 + k] = (n < NCLS) ? f2h(W[k * NCLS + n]) : (unsigned short)0;
}

// ---------------- MFMA fp16 GEMM: C = dinv .* (A[MPAD,256] * W), W given as WT[n][k] ----------------
template<bool A32, bool NARROW>
__global__ __launch_bounds__(256) void gemm_core(const void* __restrict__ Ap,
        const unsigned short* __restrict__ BT, unsigned short* __restrict__ C,
        const float* __restrict__ dinv) {
    __shared__ __align__(16) char lds[65536];   // 2 bufs x (A 16K + B 16K)
    const int t = threadIdx.x;
    const int w = t >> 6, l = t & 63;
    const int bm = blockIdx.x * 128;
    const int bn = blockIdx.y * 128;
    const int lr = l >> 3, ls = l & 7;
    const unsigned short* A16 = (const unsigned short*)Ap;
    const float* A32p = (const float*)Ap;

    auto stageB = [&](int buf, int k0) {
        char* base = lds + buf * 32768 + 16384;
#pragma unroll
        for (int i = 0; i < 4; ++i) {
            int r = w * 32 + i * 8 + lr;
            int sl = ls ^ (r & 7);
            const char* gB = (const char*)BT + (size_t)(bn + r) * 512 + (size_t)k0 * 2 + sl * 16;
            gload_lds16(gB, base + (w * 32 + i * 8) * 128);
        }
    };
    auto stageA16 = [&](int buf, int k0) {
        char* base = lds + buf * 32768;
#pragma unroll
        for (int i = 0; i < 4; ++i) {
            int r = w * 32 + i * 8 + lr;
            int sl = ls ^ (r & 7);
            const char* gA = (const char*)A16 + (size_t)(bm + r) * 512 + (size_t)k0 * 2 + sl * 16;
            gload_lds16(gA, base + (w * 32 + i * 8) * 128);
        }
    };
    float4 areg[8];
    auto issueA32 = [&](int k0) {
#pragma unroll
        for (int i = 0; i < 8; ++i) {
            int tt = i * 256 + t;
            int r = tt >> 4, q = tt & 15;
            float4 v = make_float4(0.f, 0.f, 0.f, 0.f);
            if (bm + r < NNODES) v = *(const float4*)(A32p + (size_t)(bm + r) * 256 + k0 + q * 4);
            areg[i] = v;
        }
    };
    auto writeA32 = [&](int buf) {
        char* base = lds + buf * 32768;
#pragma unroll
        for (int i = 0; i < 8; ++i) {
            int tt = i * 256 + t;
            int r = tt >> 4, q = tt & 15;
            f16 h4[4] = {(f16)areg[i].x, (f16)areg[i].y, (f16)areg[i].z, (f16)areg[i].w};
            char* dst = base + r * 128 + (((q >> 1) ^ (r & 7)) * 16) + (q & 1) * 8;
            __builtin_memcpy(dst, h4, 8);   // ds_write_b64
        }
    };

    f32x4 acc[4][4];
#pragma unroll
    for (int m = 0; m < 4; ++m)
#pragma unroll
        for (int n = 0; n < 4; ++n)
            acc[m][n] = (f32x4){0.f, 0.f, 0.f, 0.f};

    const int frow = l & 15, fk = l >> 4;
    const int r0w = (w >> 1) * 64, c0w = (w & 1) * 64;

    if constexpr (A32) { issueA32(0); } else { stageA16(0, 0); }
    stageB(0, 0);
    if constexpr (A32) { writeA32(0); }
    __syncthreads();
    for (int kt = 0; kt < 4; ++kt) {
        const int buf = kt & 1;
        if (kt < 3) {
            if constexpr (A32) { issueA32((kt + 1) * 64); } else { stageA16(buf ^ 1, (kt + 1) * 64); }
            stageB(buf ^ 1, (kt + 1) * 64);
        }
        const char* As = lds + buf * 32768;
        const char* Bs = As + 16384;
#pragma unroll
        for (int ks = 0; ks < 2; ++ks) {
            f16x8 af[4], bf[4];
#pragma unroll
            for (int m = 0; m < 4; ++m) {
                int ra = r0w + m * 16 + frow;
                af[m] = *(const f16x8*)(As + ra * 128 + (((ks * 4 + fk) ^ (ra & 7)) * 16));
            }
#pragma unroll
            for (int n = 0; n < 4; ++n) {
                int rb = c0w + n * 16 + frow;
                bf[n] = *(const f16x8*)(Bs + rb * 128 + (((ks * 4 + fk) ^ (rb & 7)) * 16));
            }
#pragma unroll
            for (int m = 0; m < 4; ++m)
#pragma unroll
                for (int n = 0; n < 4; ++n)
                    acc[m][n] = __builtin_amdgcn_mfma_f32_16x16x32_f16(af[m], bf[n], acc[m][n], 0, 0, 0);
        }
        if constexpr (A32) { if (kt < 3) writeA32(buf ^ 1); }
        __syncthreads();
    }

    // epilogue: scale rows by dinv, repack via LDS (stride 136 u16), coalesced 16B stores
    unsigned short* Cs = (unsigned short*)lds;   // [128][136]
    const int crow = (l >> 4) * 4, ccol = l & 15;
#pragma unroll
    for (int m = 0; m < 4; ++m) {
        float4 dv = *(const float4*)(dinv + bm + r0w + m * 16 + crow);
        float d4[4] = {dv.x, dv.y, dv.z, dv.w};
#pragma unroll
        for (int n = 0; n < 4; ++n)
#pragma unroll
            for (int r = 0; r < 4; ++r)
                Cs[(r0w + m * 16 + crow + r) * 136 + c0w + n * 16 + ccol] = f2h(acc[m][n][r] * d4[r]);
    }
    __syncthreads();
#pragma unroll
    for (int i = 0; i < 8; ++i) {
        int row = i * 16 + (t >> 4);
        int cs = t & 15;
        uint4 v = *(const uint4*)(Cs + row * 136 + cs * 8);
        if constexpr (NARROW) {
            if (cs < 5)
                *(uint4*)((char*)C + (size_t)(bm + row) * 80 + cs * 16) = v;
        } else {
            *(uint4*)((char*)C + (size_t)(bm + row) * 512 + bn * 2 + cs * 16) = v;
        }
    }
}

// ---------------- aggregation v5: feature-quarter x XCD partition, UNIFORM-trip loop ----------------
// Block n: r=n&7 -> quarter q=r>>1 (pins quarter to an XCD pair under blockIdx%8 round-robin);
// chunk c=(n>>3)*2+(r&1). Wave per node-quarter: 16-lane group per edge (128B quarter row),
// 2 predicated gathers per group per iteration (8 loads in flight per wave).
// Control flow mirrors the HW-validated agg_out_v3 pattern: wave-uniform trip count,
// per-lane predication inside the body only.
__global__ __launch_bounds__(256) void agg_q2(const unsigned short* __restrict__ T,
        const int* __restrict__ esrc, const int* __restrict__ offs,
        const float* __restrict__ dinv, const float* __restrict__ bias,
        unsigned short* __restrict__ outh) {
    const int n = blockIdx.x;
    const int r = n & 7;
    const int q = r >> 1;
    const int c = ((n >> 3) << 1) + (r & 1);
    const int node = c * 4 + (threadIdx.x >> 6);
    const int l = threadIdx.x & 63;
    const int g = l >> 4, sl = l & 15;
    const float one = 1.0f;
    const int e0 = offs[node], e1 = offs[node + 1];
    const int ne = e1 - e0;
    const int myidx = esrc[e0 + min(l, ne - 1)];   // cache up to 64 indices, one per lane
    const int nreg = min(ne, 64);
    const char* Tq = (const char*)T + q * 128;
    float a0 = 0.f, a1 = 0.f, a2 = 0.f, a3 = 0.f;
    for (int j = 0; j < nreg; j += 8) {            // uniform trip count
        int j0 = j + g, j1 = j + g + 4;
        int s0 = __shfl(myidx, min(j0, 63), 64);
        int s1 = __shfl(myidx, min(j1, 63), 64);
        if (j0 < nreg) {
            uint2 u = *(const uint2*)(Tq + (size_t)s0 * 512 + sl * 8);
            fmix2(a0, a1, u.x, one); fmix2(a2, a3, u.y, one);
        }
        if (j1 < nreg) {
            uint2 u = *(const uint2*)(Tq + (size_t)s1 * 512 + sl * 8);
            fmix2(a0, a1, u.x, one); fmix2(a2, a3, u.y, one);
        }
    }
    for (int e = e0 + 64 + g; e < e1; e += 4) {    // deg > 63 fallback
        int s = esrc[e];
        uint2 u = *(const uint2*)(Tq + (size_t)s * 512 + sl * 8);
        fmix2(a0, a1, u.x, one); fmix2(a2, a3, u.y, one);
    }
    a0 += __shfl_xor(a0, 16, 64); a1 += __shfl_xor(a1, 16, 64);
    a2 += __shfl_xor(a2, 16, 64); a3 += __shfl_xor(a3, 16, 64);
    a0 += __shfl_xor(a0, 32, 64); a1 += __shfl_xor(a1, 32, 64);
    a2 += __shfl_xor(a2, 32, 64); a3 += __shfl_xor(a3, 32, 64);
    if (g == 0) {
        float di = dinv[node];
        float4 bv = *(const float4*)(bias + q * 64 + sl * 4);
        float r0 = fmaxf(fmaf(a0, di, bv.x), 0.f);
        float r1 = fmaxf(fmaf(a1, di, bv.y), 0.f);
        float r2 = fmaxf(fmaf(a2, di, bv.z), 0.f);
        float r3 = fmaxf(fmaf(a3, di, bv.w), 0.f);
        uint2 o;
        o.x = (unsigned)f2h(r0) | ((unsigned)f2h(r1) << 16);
        o.y = (unsigned)f2h(r2) | ((unsigned)f2h(r3) << 16);
        *(uint2*)(outh + (size_t)node * 256 + q * 64 + sl * 4) = o;
    }
}

// ---------------- layer-3 aggregation: register indices + fma_mix; 16-lane group per edge ----------------
__global__ __launch_bounds__(256) void agg_out_v3(const unsigned short* __restrict__ T,
        const int* __restrict__ esrc, const int* __restrict__ offs,
        const float* __restrict__ dinv, const float* __restrict__ bias,
        float* __restrict__ out) {
    int node = blockIdx.x * 4 + (threadIdx.x >> 6);
    if (node >= NNODES) return;
    const int l = threadIdx.x & 63;
    const int g = l >> 4, sl = l & 15;
    const bool act = sl < 10;
    const float one = 1.0f;
    const int e0 = offs[node], e1 = offs[node + 1];
    const int ne = e1 - e0;
    const int myidx = esrc[e0 + min(l, ne - 1)];
    const int nreg = min(ne, 64);
    const char* Tb = (const char*)T;
    float a0 = 0.f, a1 = 0.f, a2 = 0.f, a3 = 0.f;
    for (int j = 0; j < nreg; j += 4) {
        int jj = j + g;
        int s = __shfl(myidx, min(jj, 63), 64);
        if (jj < nreg && act) {
            uint2 u = *(const uint2*)(Tb + (size_t)s * 80 + sl * 8);
            fmix2(a0, a1, u.x, one);
            fmix2(a2, a3, u.y, one);
        }
    }
    for (int e = e0 + 64 + g; e < e1; e += 4) {   // deg > 63 fallback
        int s = esrc[e];
        if (act) {
            uint2 u = *(const uint2*)(Tb + (size_t)s * 80 + sl * 8);
            fmix2(a0, a1, u.x, one);
            fmix2(a2, a3, u.y, one);
        }
    }
    a0 += __shfl_xor(a0, 16, 64); a1 += __shfl_xor(a1, 16, 64);
    a2 += __shfl_xor(a2, 16, 64); a3 += __shfl_xor(a3, 16, 64);
    a0 += __shfl_xor(a0, 32, 64); a1 += __shfl_xor(a1, 32, 64);
    a2 += __shfl_xor(a2, 32, 64); a3 += __shfl_xor(a3, 32, 64);
    if (g == 0 && act) {
        float di = dinv[node];
        float4 bv = *(const float4*)(bias + sl * 4);
        float4 o = make_float4(fmaf(a0, di, bv.x), fmaf(a1, di, bv.y),
                               fmaf(a2, di, bv.z), fmaf(a3, di, bv.w));
        *(float4*)(out + (size_t)node * 40 + sl * 4) = o;
    }
}

extern "C" void kernel_launch(void* const* d_in, const int* in_sizes, int n_in,
                              void* d_out, int out_size, void* d_ws, size_t ws_size,
                              hipStream_t stream) {
    const float* x  = (const float*)d_in[0];
    const int*   ei = (const int*)d_in[1];
    const float* W1 = (const float*)d_in[2];
    const float* b1 = (const float*)d_in[3];
    const float* W2 = (const float*)d_in[4];
    const float* b2 = (const float*)d_in[5];
    const float* W3 = (const float*)d_in[6];
    const float* b3 = (const float*)d_in[7];
    float* out = (float*)d_out;

    char* ws = (char*)d_ws;
    size_t o = 0;
    unsigned short* tbA  = (unsigned short*)(ws + o); o += (size_t)MPAD * 256 * 2;   // gemm out (dinv-scaled)
    unsigned short* tbB  = (unsigned short*)(ws + o); o += (size_t)MPAD * 256 * 2;   // agg out (h, relu'd)
    unsigned short* tb40 = (unsigned short*)(ws + o); o += (size_t)MPAD * NCLS * 2;  // layer-3 table
    unsigned short* W1T  = (unsigned short*)(ws + o); o += 131072;
    unsigned short* W2T  = (unsigned short*)(ws + o); o += 131072;
    unsigned short* W3T  = (unsigned short*)(ws + o); o += 65536;    // [128][256] padded
    int2* bedge  = (int2*)(ws + o);  o += (size_t)NBUCK * BCAP * 8;  // 16 MB
    int* gbcnt   = (int*)(ws + o);   o += 2048;
    int* esrc    = (int*)(ws + o);   o += (size_t)(NEDGES + NNODES) * 4;
    int* cnt     = (int*)(ws + o);   o += 400128;
    int* offs    = (int*)(ws + o);   o += 400384;
    float* dinv  = (float*)(ws + o); o += 400384;   // MPAD entries, pad=0
    int* incl    = (int*)(ws + o);   o += 400128;
    int* blksum  = (int*)(ws + o);   o += 2048;
    int* blkoff  = (int*)(ws + o);   o += 2048;
    int* flag    = (int*)(ws + o);   o += 256;
    if (ws_size < o) return;

    hipMemsetAsync(gbcnt, 0, 2048, stream);
    hipMemsetAsync(tbB + (size_t)NNODES * 256, 0, (MPAD - NNODES) * 512, stream);  // tbB pad rows

    k_detect<<<1, 64, 0, stream>>>(ei, flag);
    k_bucket<<<NBLKB, 256, 0, stream>>>(ei, flag, gbcnt, bedge);
    k_cnt<<<NBUCK, 256, 0, stream>>>(gbcnt, bedge, cnt);
    k_dinv<<<(MPAD + 255) / 256, 256, 0, stream>>>(cnt, dinv);
    k_scan1<<<NBLK_SCAN, 256, 0, stream>>>(cnt, incl, blksum);
    k_scan2<<<1, 512, 0, stream>>>(blksum, blkoff);
    k_scan3<<<NBLK_SCAN, 256, 0, stream>>>(incl, blkoff, offs);
    k_self<<<NBLK_SCAN, 256, 0, stream>>>(offs, esrc);
    k_fill2<<<NBUCK, 256, 0, stream>>>(gbcnt, bedge, offs, esrc);

    k_wt<<<256, 256, 0, stream>>>(W1, W1T);
    k_wt<<<256, 256, 0, stream>>>(W2, W2T);
    k_wt3<<<128, 256, 0, stream>>>(W3, W3T);

    dim3 gg(MPAD / 128, 2), b256(256);
    // layer 1 (A = fp32 x, read directly)
    gemm_core<true, false><<<gg, b256, 0, stream>>>(x, W1T, tbA, dinv);
    agg_q2<<<NNODES, 256, 0, stream>>>(tbA, esrc, offs, dinv, b1, tbB);
    // layer 2
    gemm_core<false, false><<<gg, b256, 0, stream>>>(tbB, W2T, tbA, dinv);
    agg_q2<<<NNODES, 256, 0, stream>>>(tbA, esrc, offs, dinv, b2, tbB);
    // layer 3 (MFMA, N padded to 128, narrow C-write)
    gemm_core<false, true><<<dim3(MPAD / 128, 1), b256, 0, stream>>>(tbB, W3T, tb40, dinv);
    agg_out_v3<<<NNODES / 4, 256, 0, stream>>>(tb40, esrc, offs, dinv, b3, out);
}

// Round 9
// 478.876 us; speedup vs baseline: 1.2873x; 1.2873x over previous
//
#include <hip/hip_runtime.h>
#include <hip/hip_bf16.h>
#include <cstdint>
#include <cstddef>

#define NNODES 100000
#define NEDGES 1600000
#define NCLS 40
#define NBLK_SCAN 391   // ceil(100000/256); 391*256 = 100096 = MPAD exactly
#define NBUCK 391       // dst>>8 buckets (256 nodes each)
#define BCAP 5120       // bucket capacity (mean 4096, +16 sigma)
#define NBLKB 256
#define CHUNK 6250      // NEDGES / NBLKB exactly
#define MPAD 100096     // 782*128, zero-padded rows

typedef _Float16 f16;
typedef _Float16 f16x8 __attribute__((ext_vector_type(8)));
typedef float f32x4 __attribute__((ext_vector_type(4)));

__device__ inline float h2f(unsigned short u) {
    f16 h; __builtin_memcpy(&h, &u, 2); return (float)h;
}
__device__ inline unsigned short f2h(float f) {
    f16 h = (f16)f; unsigned short u; __builtin_memcpy(&u, &h, 2); return u;
}
__device__ inline void gload_lds16(const void* g, void* l) {
    __builtin_amdgcn_global_load_lds((const __attribute__((address_space(1))) unsigned int*)g,
                                     (__attribute__((address_space(3))) unsigned int*)l, 16, 0, 0);
}
// a_lo += (float)f16_lo(u); a_hi += (float)f16_hi(u)  — one v_fma_mix_f32 each (bit-exact cvt+fp32 add)
__device__ inline void fmix2(float& alo, float& ahi, unsigned u, float one) {
    asm("v_fma_mix_f32 %0, %1, %2, %0 op_sel:[0,0,0] op_sel_hi:[1,0,0]"
        : "+v"(alo) : "v"(u), "v"(one));
    asm("v_fma_mix_f32 %0, %1, %2, %0 op_sel:[1,0,0] op_sel_hi:[1,0,0]"
        : "+v"(ahi) : "v"(u), "v"(one));
}

// ---------------- edge dtype detect + gbcnt zero ----------------
__global__ void k_detect(const int* __restrict__ ei, int* __restrict__ flag, int* __restrict__ gbcnt) {
    const int t = threadIdx.x;
    for (int i = t; i < NBUCK; i += 64) gbcnt[i] = 0;
    if (t == 0) {
        int nz = 0;
        for (int i = 1; i < 256; i += 2) nz |= ei[i];
        *flag = (nz == 0) ? 1 : 0;   // 1 => int64 layout
    }
}

// ---------------- bucketed edge partition (LDS histogram + grouped writes) ----------------
__global__ __launch_bounds__(256) void k_bucket(const int* __restrict__ ei,
        const int* __restrict__ flag, int* __restrict__ gbcnt, int2* __restrict__ bedge) {
    __shared__ int lcnt[NBUCK], lbase[NBUCK], lcur[NBUCK];
    const int t = threadIdx.x;
    const int is64 = *flag;
    for (int i = t; i < NBUCK; i += 256) lcnt[i] = 0;
    __syncthreads();
    const int e0 = blockIdx.x * CHUNK;
    for (int i = t; i < CHUNK; i += 256) {
        int e = e0 + i;
        int d = is64 ? ei[2 * ((size_t)NEDGES + e)] : ei[NEDGES + e];
        atomicAdd(&lcnt[d >> 8], 1);
    }
    __syncthreads();
    for (int i = t; i < NBUCK; i += 256) {
        int c = lcnt[i];
        lbase[i] = c ? atomicAdd(&gbcnt[i], c) : 0;
        lcur[i] = 0;
    }
    __syncthreads();
    for (int i = t; i < CHUNK; i += 256) {
        int e = e0 + i;
        int s, d;
        if (is64) { s = ei[2 * (size_t)e]; d = ei[2 * ((size_t)NEDGES + e)]; }
        else      { s = ei[e];             d = ei[NEDGES + e]; }
        int b = d >> 8;
        int p = lbase[b] + atomicAdd(&lcur[b], 1);
        if (p < BCAP) bedge[(size_t)b * BCAP + p] = make_int2(s, d);
    }
}

// ---------------- per-bucket node-degree count ----------------
__global__ __launch_bounds__(256) void k_cnt(const int* __restrict__ gbcnt,
        const int2* __restrict__ bedge, int* __restrict__ cnt) {
    __shared__ int lc[256];
    const int t = threadIdx.x, b = blockIdx.x;
    lc[t] = 0;
    __syncthreads();
    const int ne = min(gbcnt[b], BCAP);
    const int2* be = bedge + (size_t)b * BCAP;
    for (int i = t; i < ne; i += 256)
        atomicAdd(&lc[be[i].y & 255], 1);
    __syncthreads();
    int node = b * 256 + t;
    if (node < NNODES) cnt[node] = lc[t];
}

// ---------------- scan stage 1 over (cnt[i]+1), fused dinv ----------------
__global__ __launch_bounds__(256) void k_scan1(const int* __restrict__ cnt,
        int* __restrict__ incl, int* __restrict__ blksum, float* __restrict__ dinv) {
    __shared__ int sm[256];
    const int t = threadIdx.x;
    int i = blockIdx.x * 256 + t;      // grid covers exactly MPAD
    int cv = (i < NNODES) ? cnt[i] : 0;
    dinv[i] = (i < NNODES) ? rsqrtf((float)(cv + 1)) : 0.f;
    int v = (i < NNODES) ? (cv + 1) : 0;
    sm[t] = v;
    __syncthreads();
    for (int d = 1; d < 256; d <<= 1) {
        int x = (t >= d) ? sm[t - d] : 0;
        __syncthreads();
        sm[t] += x;
        __syncthreads();
    }
    if (i < NNODES) incl[i] = sm[t];
    if (t == 255) blksum[blockIdx.x] = sm[255];
}

__global__ __launch_bounds__(512) void k_scan2(const int* __restrict__ blksum, int* __restrict__ blkoff) {
    __shared__ int sm[512];
    const int t = threadIdx.x;
    int v = (t < NBLK_SCAN) ? blksum[t] : 0;
    sm[t] = v;
    __syncthreads();
    for (int d = 1; d < 512; d <<= 1) {
        int x = (t >= d) ? sm[t - d] : 0;
        __syncthreads();
        sm[t] += x;
        __syncthreads();
    }
    if (t < NBLK_SCAN) blkoff[t] = sm[t] - v;
}

// scan stage 3, fused self-loop placement (esrc[offs[i]] = i)
__global__ __launch_bounds__(256) void k_scan3(const int* __restrict__ incl,
        const int* __restrict__ blkoff, const int* __restrict__ cnt,
        int* __restrict__ offs, int* __restrict__ esrc) {
    int i = blockIdx.x * 256 + threadIdx.x;
    if (i < NNODES) {
        int o1 = incl[i] + blkoff[blockIdx.x];
        offs[i + 1] = o1;
        esrc[o1 - (cnt[i] + 1)] = i;   // slot 0 of node i's bucket = self edge
    }
    if (i == 0) offs[0] = 0;
}

// ---------------- per-bucket exact scatter (L2-local, block-exclusive region) ----------------
__global__ __launch_bounds__(256) void k_fill2(const int* __restrict__ gbcnt,
        const int2* __restrict__ bedge, const int* __restrict__ offs, int* __restrict__ esrc) {
    __shared__ int loff[256], lcur[256];
    const int t = threadIdx.x, b = blockIdx.x;
    int node = b * 256 + t;
    loff[t] = (node < NNODES) ? offs[node] : 0;
    lcur[t] = 0;
    __syncthreads();
    const int ne = min(gbcnt[b], BCAP);
    const int2* be = bedge + (size_t)b * BCAP;
    for (int i = t; i < ne; i += 256) {
        int2 sd = be[i];
        int li = sd.y & 255;
        int p = loff[li] + 1 + atomicAdd(&lcur[li], 1);   // +1: slot 0 is self-loop
        esrc[p] = sd.x;
    }
}

// ---------------- fused weight transposes: W1,W2 [256][256], W3 [256][40]->[128][256] padded ----------------
__global__ __launch_bounds__(256) void k_wts(const float* __restrict__ W1, const float* __restrict__ W2,
        const float* __restrict__ W3, unsigned short* __restrict__ W1T,
        unsigned short* __restrict__ W2T, unsigned short* __restrict__ W3T) {
    const int b = blockIdx.x, n = threadIdx.x;
    if (b < 256) {
        W1T[n * 256 + b] = f2h(W1[b * 256 + n]);
    } else if (b < 512) {
        int k = b - 256;
        W2T[n * 256 + k] = f2h(W2[k * 256 + n]);
    } else {
        int nn = b - 512;   // 0..127
        W3T[nn * 256 + n] = (nn < NCLS) ? f2h(W3[n * NCLS + nn]) : (unsigned short)0;
    }
}

// ---------------- MFMA fp16 GEMM: C = dinv .* (A[MPAD,256] * W), W given as WT[n][k] ----------------
template<bool A32, bool NARROW>
__global__ __launch_bounds__(256) void gemm_core(const void* __restrict__ Ap,
        const unsigned short* __restrict__ BT, unsigned short* __restrict__ C,
        const float* __restrict__ dinv) {
    __shared__ __align__(16) char lds[65536];   // 2 bufs x (A 16K + B 16K)
    const int t = threadIdx.x;
    const int w = t >> 6, l = t & 63;
    const int bm = blockIdx.x * 128;
    const int bn = blockIdx.y * 128;
    const int lr = l >> 3, ls = l & 7;
    const unsigned short* A16 = (const unsigned short*)Ap;
    const float* A32p = (const float*)Ap;

    auto stageB = [&](int buf, int k0) {
        char* base = lds + buf * 32768 + 16384;
#pragma unroll
        for (int i = 0; i < 4; ++i) {
            int r = w * 32 + i * 8 + lr;
            int sl = ls ^ (r & 7);
            const char* gB = (const char*)BT + (size_t)(bn + r) * 512 + (size_t)k0 * 2 + sl * 16;
            gload_lds16(gB, base + (w * 32 + i * 8) * 128);
        }
    };
    auto stageA16 = [&](int buf, int k0) {
        char* base = lds + buf * 32768;
#pragma unroll
        for (int i = 0; i < 4; ++i) {
            int r = w * 32 + i * 8 + lr;
            int sl = ls ^ (r & 7);
            const char* gA = (const char*)A16 + (size_t)(bm + r) * 512 + (size_t)k0 * 2 + sl * 16;
            gload_lds16(gA, base + (w * 32 + i * 8) * 128);
        }
    };
    float4 areg[8];
    auto issueA32 = [&](int k0) {
#pragma unroll
        for (int i = 0; i < 8; ++i) {
            int tt = i * 256 + t;
            int r = tt >> 4, q = tt & 15;
            float4 v = make_float4(0.f, 0.f, 0.f, 0.f);
            if (bm + r < NNODES) v = *(const float4*)(A32p + (size_t)(bm + r) * 256 + k0 + q * 4);
            areg[i] = v;
        }
    };
    auto writeA32 = [&](int buf) {
        char* base = lds + buf * 32768;
#pragma unroll
        for (int i = 0; i < 8; ++i) {
            int tt = i * 256 + t;
            int r = tt >> 4, q = tt & 15;
            f16 h4[4] = {(f16)areg[i].x, (f16)areg[i].y, (f16)areg[i].z, (f16)areg[i].w};
            char* dst = base + r * 128 + (((q >> 1) ^ (r & 7)) * 16) + (q & 1) * 8;
            __builtin_memcpy(dst, h4, 8);   // ds_write_b64
        }
    };

    f32x4 acc[4][4];
#pragma unroll
    for (int m = 0; m < 4; ++m)
#pragma unroll
        for (int n = 0; n < 4; ++n)
            acc[m][n] = (f32x4){0.f, 0.f, 0.f, 0.f};

    const int frow = l & 15, fk = l >> 4;
    const int r0w = (w >> 1) * 64, c0w = (w & 1) * 64;

    if constexpr (A32) { issueA32(0); } else { stageA16(0, 0); }
    stageB(0, 0);
    if constexpr (A32) { writeA32(0); }
    __syncthreads();
    for (int kt = 0; kt < 4; ++kt) {
        const int buf = kt & 1;
        if (kt < 3) {
            if constexpr (A32) { issueA32((kt + 1) * 64); } else { stageA16(buf ^ 1, (kt + 1) * 64); }
            stageB(buf ^ 1, (kt + 1) * 64);
        }
        const char* As = lds + buf * 32768;
        const char* Bs = As + 16384;
#pragma unroll
        for (int ks = 0; ks < 2; ++ks) {
            f16x8 af[4], bf[4];
#pragma unroll
            for (int m = 0; m < 4; ++m) {
                int ra = r0w + m * 16 + frow;
                af[m] = *(const f16x8*)(As + ra * 128 + (((ks * 4 + fk) ^ (ra & 7)) * 16));
            }
#pragma unroll
            for (int n = 0; n < 4; ++n) {
                int rb = c0w + n * 16 + frow;
                bf[n] = *(const f16x8*)(Bs + rb * 128 + (((ks * 4 + fk) ^ (rb & 7)) * 16));
            }
#pragma unroll
            for (int m = 0; m < 4; ++m)
#pragma unroll
                for (int n = 0; n < 4; ++n)
                    acc[m][n] = __builtin_amdgcn_mfma_f32_16x16x32_f16(af[m], bf[n], acc[m][n], 0, 0, 0);
        }
        if constexpr (A32) { if (kt < 3) writeA32(buf ^ 1); }
        __syncthreads();
    }

    // epilogue: scale rows by dinv, repack via LDS (stride 136 u16), coalesced 16B stores
    unsigned short* Cs = (unsigned short*)lds;   // [128][136]
    const int crow = (l >> 4) * 4, ccol = l & 15;
#pragma unroll
    for (int m = 0; m < 4; ++m) {
        float4 dv = *(const float4*)(dinv + bm + r0w + m * 16 + crow);
        float d4[4] = {dv.x, dv.y, dv.z, dv.w};
#pragma unroll
        for (int n = 0; n < 4; ++n)
#pragma unroll
            for (int r = 0; r < 4; ++r)
                Cs[(r0w + m * 16 + crow + r) * 136 + c0w + n * 16 + ccol] = f2h(acc[m][n][r] * d4[r]);
    }
    __syncthreads();
#pragma unroll
    for (int i = 0; i < 8; ++i) {
        int row = i * 16 + (t >> 4);
        int cs = t & 15;
        uint4 v = *(const uint4*)(Cs + row * 136 + cs * 8);
        if constexpr (NARROW) {
            if (cs < 5)
                *(uint4*)((char*)C + (size_t)(bm + row) * 80 + cs * 16) = v;
        } else {
            *(uint4*)((char*)C + (size_t)(bm + row) * 512 + bn * 2 + cs * 16) = v;
        }
    }
}

// ---------------- aggregation v3 (round-6 proven): register-cached indices, readlane addr, fma_mix ----------------
__global__ __launch_bounds__(256) void agg_v3(const unsigned short* __restrict__ T,
        const int* __restrict__ esrc, const int* __restrict__ offs,
        const float* __restrict__ dinv, const float* __restrict__ bias,
        unsigned short* __restrict__ outh) {
    int node = blockIdx.x * 4 + (threadIdx.x >> 6);
    if (node >= NNODES) return;
    const int l = threadIdx.x & 63;
    const float one = 1.0f;
    const int e0 = offs[node], e1 = offs[node + 1];
    const int ne = e1 - e0;
    const int myidx = esrc[e0 + min(l, ne - 1)];   // cache up to 64 indices, one per lane
    const char* Tb = (const char*)T;
    float a0 = 0.f, a1 = 0.f, a2 = 0.f, a3 = 0.f;
    const int nreg = min(ne, 64);
    int j = 0;
    for (; j + 8 <= nreg; j += 8) {
        uint2 u[8];
#pragma unroll
        for (int q = 0; q < 8; ++q) {
            int s = __builtin_amdgcn_readlane(myidx, j + q);
            u[q] = *(const uint2*)(Tb + (size_t)s * 512 + l * 8);
        }
#pragma unroll
        for (int q = 0; q < 8; ++q) {
            fmix2(a0, a1, u[q].x, one);
            fmix2(a2, a3, u[q].y, one);
        }
    }
    for (; j < nreg; ++j) {
        int s = __builtin_amdgcn_readlane(myidx, j);
        uint2 u = *(const uint2*)(Tb + (size_t)s * 512 + l * 8);
        fmix2(a0, a1, u.x, one);
        fmix2(a2, a3, u.y, one);
    }
    for (int e = e0 + 64; e < e1; ++e) {   // deg > 63 fallback (P ~ 0, must be correct)
        int s = esrc[e];
        uint2 u = *(const uint2*)(Tb + (size_t)s * 512 + l * 8);
        fmix2(a0, a1, u.x, one);
        fmix2(a2, a3, u.y, one);
    }
    float di = dinv[node];
    float4 bv = *(const float4*)(bias + l * 4);
    float r0 = fmaxf(fmaf(a0, di, bv.x), 0.f);
    float r1 = fmaxf(fmaf(a1, di, bv.y), 0.f);
    float r2 = fmaxf(fmaf(a2, di, bv.z), 0.f);
    float r3 = fmaxf(fmaf(a3, di, bv.w), 0.f);
    uint2 o;
    o.x = (unsigned)f2h(r0) | ((unsigned)f2h(r1) << 16);
    o.y = (unsigned)f2h(r2) | ((unsigned)f2h(r3) << 16);
    *(uint2*)(outh + (size_t)node * 256 + l * 4) = o;
}

// ---------------- layer-3 aggregation: register indices + fma_mix; 16-lane group per edge ----------------
__global__ __launch_bounds__(256) void agg_out_v3(const unsigned short* __restrict__ T,
        const int* __restrict__ esrc, const int* __restrict__ offs,
        const float* __restrict__ dinv, const float* __restrict__ bias,
        float* __restrict__ out) {
    int node = blockIdx.x * 4 + (threadIdx.x >> 6);
    if (node >= NNODES) return;
    const int l = threadIdx.x & 63;
    const int g = l >> 4, sl = l & 15;
    const bool act = sl < 10;
    const float one = 1.0f;
    const int e0 = offs[node], e1 = offs[node + 1];
    const int ne = e1 - e0;
    const int myidx = esrc[e0 + min(l, ne - 1)];
    const int nreg = min(ne, 64);
    const char* Tb = (const char*)T;
    float a0 = 0.f, a1 = 0.f, a2 = 0.f, a3 = 0.f;
    for (int j = 0; j < nreg; j += 4) {
        int jj = j + g;
        int s = __shfl(myidx, min(jj, 63), 64);
        if (jj < nreg && act) {
            uint2 u = *(const uint2*)(Tb + (size_t)s * 80 + sl * 8);
            fmix2(a0, a1, u.x, one);
            fmix2(a2, a3, u.y, one);
        }
    }
    for (int e = e0 + 64 + g; e < e1; e += 4) {   // deg > 63 fallback
        int s = esrc[e];
        if (act) {
            uint2 u = *(const uint2*)(Tb + (size_t)s * 80 + sl * 8);
            fmix2(a0, a1, u.x, one);
            fmix2(a2, a3, u.y, one);
        }
    }
    a0 += __shfl_xor(a0, 16, 64); a1 += __shfl_xor(a1, 16, 64);
    a2 += __shfl_xor(a2, 16, 64); a3 += __shfl_xor(a3, 16, 64);
    a0 += __shfl_xor(a0, 32, 64); a1 += __shfl_xor(a1, 32, 64);
    a2 += __shfl_xor(a2, 32, 64); a3 += __shfl_xor(a3, 32, 64);
    if (g == 0 && act) {
        float di = dinv[node];
        float4 bv = *(const float4*)(bias + sl * 4);
        float4 o = make_float4(fmaf(a0, di, bv.x), fmaf(a1, di, bv.y),
                               fmaf(a2, di, bv.z), fmaf(a3, di, bv.w));
        *(float4*)(out + (size_t)node * 40 + sl * 4) = o;
    }
}

extern "C" void kernel_launch(void* const* d_in, const int* in_sizes, int n_in,
                              void* d_out, int out_size, void* d_ws, size_t ws_size,
                              hipStream_t stream) {
    const float* x  = (const float*)d_in[0];
    const int*   ei = (const int*)d_in[1];
    const float* W1 = (const float*)d_in[2];
    const float* b1 = (const float*)d_in[3];
    const float* W2 = (const float*)d_in[4];
    const float* b2 = (const float*)d_in[5];
    const float* W3 = (const float*)d_in[6];
    const float* b3 = (const float*)d_in[7];
    float* out = (float*)d_out;

    char* ws = (char*)d_ws;
    size_t o = 0;
    unsigned short* tbA  = (unsigned short*)(ws + o); o += (size_t)MPAD * 256 * 2;   // gemm out (dinv-scaled)
    unsigned short* tbB  = (unsigned short*)(ws + o); o += (size_t)MPAD * 256 * 2;   // agg out (h, relu'd)
    unsigned short* tb40 = (unsigned short*)(ws + o); o += (size_t)MPAD * NCLS * 2;  // layer-3 table
    unsigned short* W1T  = (unsigned short*)(ws + o); o += 131072;
    unsigned short* W2T  = (unsigned short*)(ws + o); o += 131072;
    unsigned short* W3T  = (unsigned short*)(ws + o); o += 65536;    // [128][256] padded
    int2* bedge  = (int2*)(ws + o);  o += (size_t)NBUCK * BCAP * 8;  // 16 MB
    int* gbcnt   = (int*)(ws + o);   o += 2048;
    int* esrc    = (int*)(ws + o);   o += (size_t)(NEDGES + NNODES) * 4;
    int* cnt     = (int*)(ws + o);   o += 400128;
    int* offs    = (int*)(ws + o);   o += 400384;
    float* dinv  = (float*)(ws + o); o += 400384;   // MPAD entries, pad=0
    int* incl    = (int*)(ws + o);   o += 400128;
    int* blksum  = (int*)(ws + o);   o += 2048;
    int* blkoff  = (int*)(ws + o);   o += 2048;
    int* flag    = (int*)(ws + o);   o += 256;
    if (ws_size < o) return;

    hipMemsetAsync(tbB + (size_t)NNODES * 256, 0, (MPAD - NNODES) * 512, stream);  // tbB pad rows

    k_detect<<<1, 64, 0, stream>>>(ei, flag, gbcnt);
    k_bucket<<<NBLKB, 256, 0, stream>>>(ei, flag, gbcnt, bedge);
    k_cnt<<<NBUCK, 256, 0, stream>>>(gbcnt, bedge, cnt);
    k_scan1<<<NBLK_SCAN, 256, 0, stream>>>(cnt, incl, blksum, dinv);
    k_scan2<<<1, 512, 0, stream>>>(blksum, blkoff);
    k_scan3<<<NBLK_SCAN, 256, 0, stream>>>(incl, blkoff, cnt, offs, esrc);
    k_fill2<<<NBUCK, 256, 0, stream>>>(gbcnt, bedge, offs, esrc);

    k_wts<<<640, 256, 0, stream>>>(W1, W2, W3, W1T, W2T, W3T);

    dim3 gg(MPAD / 128, 2), b256(256);
    // layer 1 (A = fp32 x, read directly)
    gemm_core<true, false><<<gg, b256, 0, stream>>>(x, W1T, tbA, dinv);
    agg_v3<<<NNODES / 4, 256, 0, stream>>>(tbA, esrc, offs, dinv, b1, tbB);
    // layer 2
    gemm_core<false, false><<<gg, b256, 0, stream>>>(tbB, W2T, tbA, dinv);
    agg_v3<<<NNODES / 4, 256, 0, stream>>>(tbA, esrc, offs, dinv, b2, tbB);
    // layer 3 (MFMA, N padded to 128, narrow C-write)
    gemm_core<false, true><<<dim3(MPAD / 128, 1), b256, 0, stream>>>(tbB, W3T, tb40, dinv);
    agg_out_v3<<<NNODES / 4, 256, 0, stream>>>(tb40, esrc, offs, dinv, b3, out);
}

// Round 10
// 459.549 us; speedup vs baseline: 1.3414x; 1.0421x over previous
//
#include <hip/hip_runtime.h>
#include <hip/hip_bf16.h>
#include <cstdint>
#include <cstddef>

#define NNODES 100000
#define NEDGES 1600000
#define NCLS 40
#define NBLK_SCAN 391   // ceil(100000/256); 391*256 = 100096 = MPAD exactly
#define NBUCK 391       // dst>>8 buckets (256 nodes each)
#define BCAP 5120       // bucket capacity (mean 4096, +16 sigma)
#define NBLKB 256
#define CHUNK 6250      // NEDGES / NBLKB exactly
#define MPAD 100096     // 1564*64, zero-padded rows

typedef _Float16 f16;
typedef _Float16 f16x8 __attribute__((ext_vector_type(8)));
typedef float f32x4 __attribute__((ext_vector_type(4)));

__device__ inline float h2f(unsigned short u) {
    f16 h; __builtin_memcpy(&h, &u, 2); return (float)h;
}
__device__ inline unsigned short f2h(float f) {
    f16 h = (f16)f; unsigned short u; __builtin_memcpy(&u, &h, 2); return u;
}
__device__ inline void gload_lds16(const void* g, void* l) {
    __builtin_amdgcn_global_load_lds((const __attribute__((address_space(1))) unsigned int*)g,
                                     (__attribute__((address_space(3))) unsigned int*)l, 16, 0, 0);
}
// a_lo += (float)f16_lo(u); a_hi += (float)f16_hi(u)  — one v_fma_mix_f32 each (bit-exact cvt+fp32 add)
__device__ inline void fmix2(float& alo, float& ahi, unsigned u, float one) {
    asm("v_fma_mix_f32 %0, %1, %2, %0 op_sel:[0,0,0] op_sel_hi:[1,0,0]"
        : "+v"(alo) : "v"(u), "v"(one));
    asm("v_fma_mix_f32 %0, %1, %2, %0 op_sel:[1,0,0] op_sel_hi:[1,0,0]"
        : "+v"(ahi) : "v"(u), "v"(one));
}

// ---------------- fused prep: weight transposes + tbB pad zero + edge-dtype detect + gbcnt zero ----------------
__global__ __launch_bounds__(256) void k_wts(const float* __restrict__ W1, const float* __restrict__ W2,
        const float* __restrict__ W3, unsigned short* __restrict__ W1T,
        unsigned short* __restrict__ W2T, unsigned short* __restrict__ W3T,
        unsigned short* __restrict__ tbBpad, const int* __restrict__ ei,
        int* __restrict__ flag, int* __restrict__ gbcnt) {
    const int b = blockIdx.x, n = threadIdx.x;
    if (b < 256) {
        W1T[n * 256 + b] = f2h(W1[b * 256 + n]);
    } else if (b < 512) {
        int k = b - 256;
        W2T[n * 256 + k] = f2h(W2[k * 256 + n]);
    } else if (b < 640) {
        int nn = b - 512;   // 0..127
        W3T[nn * 256 + n] = (nn < NCLS) ? f2h(W3[n * NCLS + nn]) : (unsigned short)0;
        int idx = nn * 256 + n;
        if (idx < (MPAD - NNODES) * 256) tbBpad[idx] = 0;
    } else {
        for (int i = n; i < NBUCK; i += 256) gbcnt[i] = 0;
        if (n == 0) {
            int nz = 0;
            for (int i = 1; i < 256; i += 2) nz |= ei[i];
            *flag = (nz == 0) ? 1 : 0;   // 1 => int64 layout
        }
    }
}

// ---------------- bucketed edge partition (LDS histogram + grouped writes, packed arrays) ----------------
__global__ __launch_bounds__(256) void k_bucket(const int* __restrict__ ei,
        const int* __restrict__ flag, int* __restrict__ gbcnt,
        int* __restrict__ bsrc, unsigned char* __restrict__ bdst8) {
    __shared__ int lcnt[NBUCK], lbase[NBUCK], lcur[NBUCK];
    const int t = threadIdx.x;
    const int is64 = *flag;
    for (int i = t; i < NBUCK; i += 256) lcnt[i] = 0;
    __syncthreads();
    const int e0 = blockIdx.x * CHUNK;
    for (int i = t; i < CHUNK; i += 256) {
        int e = e0 + i;
        int d = is64 ? ei[2 * ((size_t)NEDGES + e)] : ei[NEDGES + e];
        atomicAdd(&lcnt[d >> 8], 1);
    }
    __syncthreads();
    for (int i = t; i < NBUCK; i += 256) {
        int c = lcnt[i];
        lbase[i] = c ? atomicAdd(&gbcnt[i], c) : 0;
        lcur[i] = 0;
    }
    __syncthreads();
    for (int i = t; i < CHUNK; i += 256) {
        int e = e0 + i;
        int s, d;
        if (is64) { s = ei[2 * (size_t)e]; d = ei[2 * ((size_t)NEDGES + e)]; }
        else      { s = ei[e];             d = ei[NEDGES + e]; }
        int b = d >> 8;
        int p = lbase[b] + atomicAdd(&lcur[b], 1);
        if (p < BCAP) {
            bsrc[(size_t)b * BCAP + p] = s;
            bdst8[(size_t)b * BCAP + p] = (unsigned char)(d & 255);
        }
    }
}

// ---------------- per-bucket node-degree count (reads 1B/edge) ----------------
__global__ __launch_bounds__(256) void k_cnt(const int* __restrict__ gbcnt,
        const unsigned char* __restrict__ bdst8, int* __restrict__ cnt) {
    __shared__ int lc[256];
    const int t = threadIdx.x, b = blockIdx.x;
    lc[t] = 0;
    __syncthreads();
    const int ne = min(gbcnt[b], BCAP);
    const unsigned char* bd = bdst8 + (size_t)b * BCAP;
    for (int i = t; i < ne; i += 256)
        atomicAdd(&lc[bd[i]], 1);
    __syncthreads();
    int node = b * 256 + t;
    if (node < NNODES) cnt[node] = lc[t];
}

// ---------------- scan stage 1 over (cnt[i]+1), fused dinv ----------------
__global__ __launch_bounds__(256) void k_scan1(const int* __restrict__ cnt,
        int* __restrict__ incl, int* __restrict__ blksum, float* __restrict__ dinv) {
    __shared__ int sm[256];
    const int t = threadIdx.x;
    int i = blockIdx.x * 256 + t;      // grid covers exactly MPAD
    int cv = (i < NNODES) ? cnt[i] : 0;
    dinv[i] = (i < NNODES) ? rsqrtf((float)(cv + 1)) : 0.f;
    int v = (i < NNODES) ? (cv + 1) : 0;
    sm[t] = v;
    __syncthreads();
    for (int d = 1; d < 256; d <<= 1) {
        int x = (t >= d) ? sm[t - d] : 0;
        __syncthreads();
        sm[t] += x;
        __syncthreads();
    }
    if (i < NNODES) incl[i] = sm[t];
    if (t == 255) blksum[blockIdx.x] = sm[255];
}

__global__ __launch_bounds__(512) void k_scan2(const int* __restrict__ blksum, int* __restrict__ blkoff) {
    __shared__ int sm[512];
    const int t = threadIdx.x;
    int v = (t < NBLK_SCAN) ? blksum[t] : 0;
    sm[t] = v;
    __syncthreads();
    for (int d = 1; d < 512; d <<= 1) {
        int x = (t >= d) ? sm[t - d] : 0;
        __syncthreads();
        sm[t] += x;
        __syncthreads();
    }
    if (t < NBLK_SCAN) blkoff[t] = sm[t] - v;
}

// scan stage 3, fused self-loop placement (esrc[offs[i]] = i)
__global__ __launch_bounds__(256) void k_scan3(const int* __restrict__ incl,
        const int* __restrict__ blkoff, const int* __restrict__ cnt,
        int* __restrict__ offs, int* __restrict__ esrc) {
    int i = blockIdx.x * 256 + threadIdx.x;
    if (i < NNODES) {
        int o1 = incl[i] + blkoff[blockIdx.x];
        offs[i + 1] = o1;
        esrc[o1 - (cnt[i] + 1)] = i;   // slot 0 of node i's bucket = self edge
    }
    if (i == 0) offs[0] = 0;
}

// ---------------- per-bucket exact scatter (L2-local, block-exclusive region) ----------------
__global__ __launch_bounds__(256) void k_fill2(const int* __restrict__ gbcnt,
        const int* __restrict__ bsrc, const unsigned char* __restrict__ bdst8,
        const int* __restrict__ offs, int* __restrict__ esrc) {
    __shared__ int loff[256], lcur[256];
    const int t = threadIdx.x, b = blockIdx.x;
    int node = b * 256 + t;
    loff[t] = (node < NNODES) ? offs[node] : 0;
    lcur[t] = 0;
    __syncthreads();
    const int ne = min(gbcnt[b], BCAP);
    const int* bs = bsrc + (size_t)b * BCAP;
    const unsigned char* bd = bdst8 + (size_t)b * BCAP;
    for (int i = t; i < ne; i += 256) {
        int s = bs[i];
        int li = bd[i];
        int p = loff[li] + 1 + atomicAdd(&lcur[li], 1);   // +1: slot 0 is self-loop
        esrc[p] = s;
    }
}

// ---------------- MFMA fp16 GEMM, single-pass A: BM=64, BN=256, BK=64, 4 waves ----------------
// C[MPAD,256] = dinv .* (A[MPAD,256] * W), W given as WT[n][k].
// Wave w owns the 64x64 quadrant cols w*64..+63. A staged once per block (no N-direction re-read).
// Same 128B-row XOR-slot swizzle as the proven 128x128 kernel.
template<bool A32>
__global__ __launch_bounds__(256) void gemm_w(const void* __restrict__ Ap,
        const unsigned short* __restrict__ BT, unsigned short* __restrict__ C,
        const float* __restrict__ dinv) {
    __shared__ __align__(16) char lds[81920];   // 2 bufs x (A 8K + B 32K)
    const int t = threadIdx.x;
    const int w = t >> 6, l = t & 63;
    const int bm = blockIdx.x * 64;
    const int lr = l >> 3, ls = l & 7;
    const unsigned short* A16 = (const unsigned short*)Ap;
    const float* A32p = (const float*)Ap;

    auto stageB = [&](int buf, int k0) {
        char* base = lds + buf * 40960 + 8192;
#pragma unroll
        for (int i = 0; i < 8; ++i) {
            int r = w * 64 + i * 8 + lr;          // 0..255 over WT rows
            int sl = ls ^ (r & 7);
            const char* gB = (const char*)BT + (size_t)r * 512 + (size_t)k0 * 2 + sl * 16;
            gload_lds16(gB, base + (w * 64 + i * 8) * 128);
        }
    };
    auto stageA16 = [&](int buf, int k0) {
        char* base = lds + buf * 40960;
#pragma unroll
        for (int i = 0; i < 2; ++i) {
            int r = w * 16 + i * 8 + lr;          // 0..63
            int sl = ls ^ (r & 7);
            const char* gA = (const char*)A16 + (size_t)(bm + r) * 512 + (size_t)k0 * 2 + sl * 16;
            gload_lds16(gA, base + (w * 16 + i * 8) * 128);
        }
    };
    float4 areg[4];
    const int arow = t >> 2, akq = (t & 3) << 4;   // row 0..63, k-offset 0/16/32/48
    auto issueA32 = [&](int k0) {
#pragma unroll
        for (int i = 0; i < 4; ++i) {
            float4 v = make_float4(0.f, 0.f, 0.f, 0.f);
            if (bm + arow < NNODES) v = *(const float4*)(A32p + (size_t)(bm + arow) * 256 + k0 + akq + i * 4);
            areg[i] = v;
        }
    };
    auto writeA32 = [&](int buf) {
        char* base = lds + buf * 40960;
        f16 h[16];
#pragma unroll
        for (int i = 0; i < 4; ++i) {
            h[i * 4 + 0] = (f16)areg[i].x; h[i * 4 + 1] = (f16)areg[i].y;
            h[i * 4 + 2] = (f16)areg[i].z; h[i * 4 + 3] = (f16)areg[i].w;
        }
        int s0 = (t & 3) * 2;                       // logical slots s0, s0+1
        char* d0 = base + arow * 128 + ((s0 ^ (arow & 7)) * 16);
        char* d1 = base + arow * 128 + (((s0 + 1) ^ (arow & 7)) * 16);
        __builtin_memcpy(d0, &h[0], 16);            // ds_write_b128
        __builtin_memcpy(d1, &h[8], 16);
    };

    f32x4 acc[4][4];
#pragma unroll
    for (int m = 0; m < 4; ++m)
#pragma unroll
        for (int n = 0; n < 4; ++n)
            acc[m][n] = (f32x4){0.f, 0.f, 0.f, 0.f};

    const int frow = l & 15, fk = l >> 4;

    if constexpr (A32) { issueA32(0); } else { stageA16(0, 0); }
    stageB(0, 0);
    if constexpr (A32) { writeA32(0); }
    __syncthreads();
    for (int kt = 0; kt < 4; ++kt) {
        const int buf = kt & 1;
        if (kt < 3) {
            if constexpr (A32) { issueA32((kt + 1) * 64); } else { stageA16(buf ^ 1, (kt + 1) * 64); }
            stageB(buf ^ 1, (kt + 1) * 64);
        }
        const char* As = lds + buf * 40960;
        const char* Bs = As + 8192;
#pragma unroll
        for (int ks = 0; ks < 2; ++ks) {
            f16x8 af[4], bf[4];
#pragma unroll
            for (int m = 0; m < 4; ++m) {
                int ra = m * 16 + frow;
                af[m] = *(const f16x8*)(As + ra * 128 + (((ks * 4 + fk) ^ (ra & 7)) * 16));
            }
#pragma unroll
            for (int n = 0; n < 4; ++n) {
                int rb = w * 64 + n * 16 + frow;
                bf[n] = *(const f16x8*)(Bs + rb * 128 + (((ks * 4 + fk) ^ (rb & 7)) * 16));
            }
#pragma unroll
            for (int m = 0; m < 4; ++m)
#pragma unroll
                for (int n = 0; n < 4; ++n)
                    acc[m][n] = __builtin_amdgcn_mfma_f32_16x16x32_f16(af[m], bf[n], acc[m][n], 0, 0, 0);
        }
        if constexpr (A32) { if (kt < 3) writeA32(buf ^ 1); }
        __syncthreads();
    }

    // epilogue: scale rows by dinv, repack via LDS [64][264], coalesced 16B stores
    unsigned short* Cs = (unsigned short*)lds;
    const int crow = (l >> 4) * 4, ccol = l & 15;
#pragma unroll
    for (int m = 0; m < 4; ++m) {
        float4 dv = *(const float4*)(dinv + bm + m * 16 + crow);
        float d4[4] = {dv.x, dv.y, dv.z, dv.w};
#pragma unroll
        for (int n = 0; n < 4; ++n)
#pragma unroll
            for (int r = 0; r < 4; ++r)
                Cs[(m * 16 + crow + r) * 264 + w * 64 + n * 16 + ccol] = f2h(acc[m][n][r] * d4[r]);
    }
    __syncthreads();
#pragma unroll
    for (int i = 0; i < 8; ++i) {
        int idx = i * 256 + t;
        int row = idx >> 5, cs = idx & 31;
        uint4 v = *(const uint4*)(Cs + row * 264 + cs * 8);
        *(uint4*)((char*)C + (size_t)(bm + row) * 512 + cs * 16) = v;
    }
}

// ---------------- layer-3 MFMA GEMM (proven 128x128 kernel, narrow C-write) ----------------
__global__ __launch_bounds__(256) void gemm_n(const unsigned short* __restrict__ A16,
        const unsigned short* __restrict__ BT, unsigned short* __restrict__ C,
        const float* __restrict__ dinv) {
    __shared__ __align__(16) char lds[65536];
    const int t = threadIdx.x;
    const int w = t >> 6, l = t & 63;
    const int bm = blockIdx.x * 128;
    const int lr = l >> 3, ls = l & 7;

    auto stage = [&](int buf, int k0) {
        char* base = lds + buf * 32768;
#pragma unroll
        for (int i = 0; i < 4; ++i) {
            int r = w * 32 + i * 8 + lr;
            int sl = ls ^ (r & 7);
            const char* gA = (const char*)A16 + (size_t)(bm + r) * 512 + (size_t)k0 * 2 + sl * 16;
            gload_lds16(gA, base + (w * 32 + i * 8) * 128);
            const char* gB = (const char*)BT + (size_t)r * 512 + (size_t)k0 * 2 + sl * 16;
            gload_lds16(gB, base + 16384 + (w * 32 + i * 8) * 128);
        }
    };

    f32x4 acc[4][4];
#pragma unroll
    for (int m = 0; m < 4; ++m)
#pragma unroll
        for (int n = 0; n < 4; ++n)
            acc[m][n] = (f32x4){0.f, 0.f, 0.f, 0.f};

    const int frow = l & 15, fk = l >> 4;
    const int r0w = (w >> 1) * 64, c0w = (w & 1) * 64;

    stage(0, 0);
    __syncthreads();
    for (int kt = 0; kt < 4; ++kt) {
        const int buf = kt & 1;
        if (kt < 3) stage(buf ^ 1, (kt + 1) * 64);
        const char* As = lds + buf * 32768;
        const char* Bs = As + 16384;
#pragma unroll
        for (int ks = 0; ks < 2; ++ks) {
            f16x8 af[4], bf[4];
#pragma unroll
            for (int m = 0; m < 4; ++m) {
                int ra = r0w + m * 16 + frow;
                af[m] = *(const f16x8*)(As + ra * 128 + (((ks * 4 + fk) ^ (ra & 7)) * 16));
            }
#pragma unroll
            for (int n = 0; n < 4; ++n) {
                int rb = c0w + n * 16 + frow;
                bf[n] = *(const f16x8*)(Bs + rb * 128 + (((ks * 4 + fk) ^ (rb & 7)) * 16));
            }
#pragma unroll
            for (int m = 0; m < 4; ++m)
#pragma unroll
                for (int n = 0; n < 4; ++n)
                    acc[m][n] = __builtin_amdgcn_mfma_f32_16x16x32_f16(af[m], bf[n], acc[m][n], 0, 0, 0);
        }
        __syncthreads();
    }

    unsigned short* Cs = (unsigned short*)lds;   // [128][136]
    const int crow = (l >> 4) * 4, ccol = l & 15;
#pragma unroll
    for (int m = 0; m < 4; ++m) {
        float4 dv = *(const float4*)(dinv + bm + r0w + m * 16 + crow);
        float d4[4] = {dv.x, dv.y, dv.z, dv.w};
#pragma unroll
        for (int n = 0; n < 4; ++n)
#pragma unroll
            for (int r = 0; r < 4; ++r)
                Cs[(r0w + m * 16 + crow + r) * 136 + c0w + n * 16 + ccol] = f2h(acc[m][n][r] * d4[r]);
    }
    __syncthreads();
#pragma unroll
    for (int i = 0; i < 8; ++i) {
        int row = i * 16 + (t >> 4);
        int cs = t & 15;
        if (cs < 5) {
            uint4 v = *(const uint4*)(Cs + row * 136 + cs * 8);
            *(uint4*)((char*)C + (size_t)(bm + row) * 80 + cs * 16) = v;
        }
    }
}

// ---------------- aggregation v3 (proven): register-cached indices, readlane addr, fma_mix ----------------
__global__ __launch_bounds__(256) void agg_v3(const unsigned short* __restrict__ T,
        const int* __restrict__ esrc, const int* __restrict__ offs,
        const float* __restrict__ dinv, const float* __restrict__ bias,
        unsigned short* __restrict__ outh) {
    int node = blockIdx.x * 4 + (threadIdx.x >> 6);
    if (node >= NNODES) return;
    const int l = threadIdx.x & 63;
    const float one = 1.0f;
    const int e0 = offs[node], e1 = offs[node + 1];
    const int ne = e1 - e0;
    const int myidx = esrc[e0 + min(l, ne - 1)];   // cache up to 64 indices, one per lane
    const char* Tb = (const char*)T;
    float a0 = 0.f, a1 = 0.f, a2 = 0.f, a3 = 0.f;
    const int nreg = min(ne, 64);
    int j = 0;
    for (; j + 8 <= nreg; j += 8) {
        uint2 u[8];
#pragma unroll
        for (int q = 0; q < 8; ++q) {
            int s = __builtin_amdgcn_readlane(myidx, j + q);
            u[q] = *(const uint2*)(Tb + (size_t)s * 512 + l * 8);
        }
#pragma unroll
        for (int q = 0; q < 8; ++q) {
            fmix2(a0, a1, u[q].x, one);
            fmix2(a2, a3, u[q].y, one);
        }
    }
    for (; j < nreg; ++j) {
        int s = __builtin_amdgcn_readlane(myidx, j);
        uint2 u = *(const uint2*)(Tb + (size_t)s * 512 + l * 8);
        fmix2(a0, a1, u.x, one);
        fmix2(a2, a3, u.y, one);
    }
    for (int e = e0 + 64; e < e1; ++e) {   // deg > 63 fallback
        int s = esrc[e];
        uint2 u = *(const uint2*)(Tb + (size_t)s * 512 + l * 8);
        fmix2(a0, a1, u.x, one);
        fmix2(a2, a3, u.y, one);
    }
    float di = dinv[node];
    float4 bv = *(const float4*)(bias + l * 4);
    float r0 = fmaxf(fmaf(a0, di, bv.x), 0.f);
    float r1 = fmaxf(fmaf(a1, di, bv.y), 0.f);
    float r2 = fmaxf(fmaf(a2, di, bv.z), 0.f);
    float r3 = fmaxf(fmaf(a3, di, bv.w), 0.f);
    uint2 o;
    o.x = (unsigned)f2h(r0) | ((unsigned)f2h(r1) << 16);
    o.y = (unsigned)f2h(r2) | ((unsigned)f2h(r3) << 16);
    *(uint2*)(outh + (size_t)node * 256 + l * 4) = o;
}

// ---------------- layer-3 aggregation: register indices + fma_mix; 16-lane group per edge ----------------
__global__ __launch_bounds__(256) void agg_out_v3(const unsigned short* __restrict__ T,
        const int* __restrict__ esrc, const int* __restrict__ offs,
        const float* __restrict__ dinv, const float* __restrict__ bias,
        float* __restrict__ out) {
    int node = blockIdx.x * 4 + (threadIdx.x >> 6);
    if (node >= NNODES) return;
    const int l = threadIdx.x & 63;
    const int g = l >> 4, sl = l & 15;
    const bool act = sl < 10;
    const float one = 1.0f;
    const int e0 = offs[node], e1 = offs[node + 1];
    const int ne = e1 - e0;
    const int myidx = esrc[e0 + min(l, ne - 1)];
    const int nreg = min(ne, 64);
    const char* Tb = (const char*)T;
    float a0 = 0.f, a1 = 0.f, a2 = 0.f, a3 = 0.f;
    for (int j = 0; j < nreg; j += 4) {
        int jj = j + g;
        int s = __shfl(myidx, min(jj, 63), 64);
        if (jj < nreg && act) {
            uint2 u = *(const uint2*)(Tb + (size_t)s * 80 + sl * 8);
            fmix2(a0, a1, u.x, one);
            fmix2(a2, a3, u.y, one);
        }
    }
    for (int e = e0 + 64 + g; e < e1; e += 4) {   // deg > 63 fallback
        int s = esrc[e];
        if (act) {
            uint2 u = *(const uint2*)(Tb + (size_t)s * 80 + sl * 8);
            fmix2(a0, a1, u.x, one);
            fmix2(a2, a3, u.y, one);
        }
    }
    a0 += __shfl_xor(a0, 16, 64); a1 += __shfl_xor(a1, 16, 64);
    a2 += __shfl_xor(a2, 16, 64); a3 += __shfl_xor(a3, 16, 64);
    a0 += __shfl_xor(a0, 32, 64); a1 += __shfl_xor(a1, 32, 64);
    a2 += __shfl_xor(a2, 32, 64); a3 += __shfl_xor(a3, 32, 64);
    if (g == 0 && act) {
        float di = dinv[node];
        float4 bv = *(const float4*)(bias + sl * 4);
        float4 o = make_float4(fmaf(a0, di, bv.x), fmaf(a1, di, bv.y),
                               fmaf(a2, di, bv.z), fmaf(a3, di, bv.w));
        *(float4*)(out + (size_t)node * 40 + sl * 4) = o;
    }
}

extern "C" void kernel_launch(void* const* d_in, const int* in_sizes, int n_in,
                              void* d_out, int out_size, void* d_ws, size_t ws_size,
                              hipStream_t stream) {
    const float* x  = (const float*)d_in[0];
    const int*   ei = (const int*)d_in[1];
    const float* W1 = (const float*)d_in[2];
    const float* b1 = (const float*)d_in[3];
    const float* W2 = (const float*)d_in[4];
    const float* b2 = (const float*)d_in[5];
    const float* W3 = (const float*)d_in[6];
    const float* b3 = (const float*)d_in[7];
    float* out = (float*)d_out;

    char* ws = (char*)d_ws;
    size_t o = 0;
    unsigned short* tbA  = (unsigned short*)(ws + o); o += (size_t)MPAD * 256 * 2;   // gemm out (dinv-scaled)
    unsigned short* tbB  = (unsigned short*)(ws + o); o += (size_t)MPAD * 256 * 2;   // agg out (h, relu'd)
    unsigned short* tb40 = (unsigned short*)(ws + o); o += (size_t)MPAD * NCLS * 2;  // layer-3 table
    unsigned short* W1T  = (unsigned short*)(ws + o); o += 131072;
    unsigned short* W2T  = (unsigned short*)(ws + o); o += 131072;
    unsigned short* W3T  = (unsigned short*)(ws + o); o += 65536;    // [128][256] padded
    int* bsrc    = (int*)(ws + o);   o += (size_t)NBUCK * BCAP * 4;  // 8 MB
    unsigned char* bdst8 = (unsigned char*)(ws + o); o += (size_t)NBUCK * BCAP + 256;
    int* gbcnt   = (int*)(ws + o);   o += 2048;
    int* esrc    = (int*)(ws + o);   o += (size_t)(NEDGES + NNODES) * 4;
    int* cnt     = (int*)(ws + o);   o += 400128;
    int* offs    = (int*)(ws + o);   o += 400384;
    float* dinv  = (float*)(ws + o); o += 400384;   // MPAD entries, pad=0
    int* incl    = (int*)(ws + o);   o += 400128;
    int* blksum  = (int*)(ws + o);   o += 2048;
    int* blkoff  = (int*)(ws + o);   o += 2048;
    int* flag    = (int*)(ws + o);   o += 256;
    if (ws_size < o) return;

    // prep (weights + detect + gbcnt zero + tbB pad zero) first; graph build next
    k_wts<<<641, 256, 0, stream>>>(W1, W2, W3, W1T, W2T, W3T,
                                   tbB + (size_t)NNODES * 256, ei, flag, gbcnt);
    k_bucket<<<NBLKB, 256, 0, stream>>>(ei, flag, gbcnt, bsrc, bdst8);
    k_cnt<<<NBUCK, 256, 0, stream>>>(gbcnt, bdst8, cnt);
    k_scan1<<<NBLK_SCAN, 256, 0, stream>>>(cnt, incl, blksum, dinv);
    k_scan2<<<1, 512, 0, stream>>>(blksum, blkoff);
    k_scan3<<<NBLK_SCAN, 256, 0, stream>>>(incl, blkoff, cnt, offs, esrc);
    k_fill2<<<NBUCK, 256, 0, stream>>>(gbcnt, bsrc, bdst8, offs, esrc);

    dim3 b256(256);
    // layer 1 (A = fp32 x, read once)
    gemm_w<true><<<MPAD / 64, b256, 0, stream>>>(x, W1T, tbA, dinv);
    agg_v3<<<NNODES / 4, 256, 0, stream>>>(tbA, esrc, offs, dinv, b1, tbB);
    // layer 2
    gemm_w<false><<<MPAD / 64, b256, 0, stream>>>(tbB, W2T, tbA, dinv);
    agg_v3<<<NNODES / 4, 256, 0, stream>>>(tbA, esrc, offs, dinv, b2, tbB);
    // layer 3 (proven 128x128 kernel, narrow C-write)
    gemm_n<<<MPAD / 128, b256, 0, stream>>>(tbB, W3T, tb40, dinv);
    agg_out_v3<<<NNODES / 4, 256, 0, stream>>>(tb40, esrc, offs, dinv, b3, out);
}

// Round 11
// 440.393 us; speedup vs baseline: 1.3998x; 1.0435x over previous
//
#include <hip/hip_runtime.h>
#include <hip/hip_bf16.h>
#include <cstdint>
#include <cstddef>

#define NNODES 100000
#define NEDGES 1600000
#define NCLS 40
#define NBLK_SCAN 391   // ceil(100000/256); 391*256 = 100096 = MPAD exactly
#define NBUCK 391       // dst>>8 buckets (256 nodes each)
#define BCAP 5120       // bucket capacity (mean 4096, +16 sigma)
#define NBLKB 256
#define CHUNK 6250      // NEDGES / NBLKB exactly
#define MPAD 100096     // 1564*64, zero-padded rows

typedef _Float16 f16;
typedef _Float16 f16x8 __attribute__((ext_vector_type(8)));
typedef float f32x4 __attribute__((ext_vector_type(4)));

__device__ inline float h2f(unsigned short u) {
    f16 h; __builtin_memcpy(&h, &u, 2); return (float)h;
}
__device__ inline unsigned short f2h(float f) {
    f16 h = (f16)f; unsigned short u; __builtin_memcpy(&u, &h, 2); return u;
}
__device__ inline void gload_lds16(const void* g, void* l) {
    __builtin_amdgcn_global_load_lds((const __attribute__((address_space(1))) unsigned int*)g,
                                     (__attribute__((address_space(3))) unsigned int*)l, 16, 0, 0);
}
// a_lo += (float)f16_lo(u); a_hi += (float)f16_hi(u)  — one v_fma_mix_f32 each (bit-exact cvt+fp32 add)
__device__ inline void fmix2(float& alo, float& ahi, unsigned u, float one) {
    asm("v_fma_mix_f32 %0, %1, %2, %0 op_sel:[0,0,0] op_sel_hi:[1,0,0]"
        : "+v"(alo) : "v"(u), "v"(one));
    asm("v_fma_mix_f32 %0, %1, %2, %0 op_sel:[1,0,0] op_sel_hi:[1,0,0]"
        : "+v"(ahi) : "v"(u), "v"(one));
}

// ---------------- fused prep: weight transposes + tbB pad zero + edge-dtype detect + gbcnt zero ----------------
__global__ __launch_bounds__(256) void k_wts(const float* __restrict__ W1, const float* __restrict__ W2,
        const float* __restrict__ W3, unsigned short* __restrict__ W1T,
        unsigned short* __restrict__ W2T, unsigned short* __restrict__ W3T,
        unsigned short* __restrict__ tbBpad, const int* __restrict__ ei,
        int* __restrict__ flag, int* __restrict__ gbcnt) {
    const int b = blockIdx.x, n = threadIdx.x;
    if (b < 256) {
        W1T[n * 256 + b] = f2h(W1[b * 256 + n]);
    } else if (b < 512) {
        int k = b - 256;
        W2T[n * 256 + k] = f2h(W2[k * 256 + n]);
    } else if (b < 640) {
        int nn = b - 512;   // 0..127
        W3T[nn * 256 + n] = (nn < NCLS) ? f2h(W3[n * NCLS + nn]) : (unsigned short)0;
        int idx = nn * 256 + n;
        if (idx < (MPAD - NNODES) * 256) tbBpad[idx] = 0;
    } else {
        for (int i = n; i < NBUCK; i += 256) gbcnt[i] = 0;
        if (n == 0) {
            int nz = 0;
            for (int i = 1; i < 256; i += 2) nz |= ei[i];
            *flag = (nz == 0) ? 1 : 0;   // 1 => int64 layout
        }
    }
}

// ---------------- bucketed edge partition (LDS histogram + grouped writes, packed arrays) ----------------
__global__ __launch_bounds__(256) void k_bucket(const int* __restrict__ ei,
        const int* __restrict__ flag, int* __restrict__ gbcnt,
        int* __restrict__ bsrc, unsigned char* __restrict__ bdst8) {
    __shared__ int lcnt[NBUCK], lbase[NBUCK], lcur[NBUCK];
    const int t = threadIdx.x;
    const int is64 = *flag;
    for (int i = t; i < NBUCK; i += 256) lcnt[i] = 0;
    __syncthreads();
    const int e0 = blockIdx.x * CHUNK;
    for (int i = t; i < CHUNK; i += 256) {
        int e = e0 + i;
        int d = is64 ? ei[2 * ((size_t)NEDGES + e)] : ei[NEDGES + e];
        atomicAdd(&lcnt[d >> 8], 1);
    }
    __syncthreads();
    for (int i = t; i < NBUCK; i += 256) {
        int c = lcnt[i];
        lbase[i] = c ? atomicAdd(&gbcnt[i], c) : 0;
        lcur[i] = 0;
    }
    __syncthreads();
    for (int i = t; i < CHUNK; i += 256) {
        int e = e0 + i;
        int s, d;
        if (is64) { s = ei[2 * (size_t)e]; d = ei[2 * ((size_t)NEDGES + e)]; }
        else      { s = ei[e];             d = ei[NEDGES + e]; }
        int b = d >> 8;
        int p = lbase[b] + atomicAdd(&lcur[b], 1);
        if (p < BCAP) {
            bsrc[(size_t)b * BCAP + p] = s;
            bdst8[(size_t)b * BCAP + p] = (unsigned char)(d & 255);
        }
    }
}

// ---------------- fused: per-bucket degree count + dinv + block scan (stage 1) ----------------
__global__ __launch_bounds__(256) void k_cntscan(const int* __restrict__ gbcnt,
        const unsigned char* __restrict__ bdst8, int* __restrict__ cnt,
        float* __restrict__ dinv, int* __restrict__ incl, int* __restrict__ blksum) {
    __shared__ int lc[256];
    __shared__ int sm[256];
    const int t = threadIdx.x, b = blockIdx.x;
    lc[t] = 0;
    __syncthreads();
    const int ne = min(gbcnt[b], BCAP);
    const unsigned char* bd = bdst8 + (size_t)b * BCAP;
    for (int i = t; i < ne; i += 256)
        atomicAdd(&lc[bd[i]], 1);
    __syncthreads();
    const int node = b * 256 + t;            // node < MPAD always
    const int cv = lc[t];
    const bool valid = node < NNODES;
    if (valid) cnt[node] = cv;
    dinv[node] = valid ? rsqrtf((float)(cv + 1)) : 0.f;
    int v = valid ? (cv + 1) : 0;
    sm[t] = v;
    __syncthreads();
    for (int d = 1; d < 256; d <<= 1) {
        int x = (t >= d) ? sm[t - d] : 0;
        __syncthreads();
        sm[t] += x;
        __syncthreads();
    }
    if (valid) incl[node] = sm[t];
    if (t == 255) blksum[b] = sm[255];
}

// ---------------- fused: block-offset sum (stage 2) + offs + self-loop placement (stage 3) ----------------
__global__ __launch_bounds__(256) void k_scan23(const int* __restrict__ blksum,
        const int* __restrict__ incl, const int* __restrict__ cnt,
        int* __restrict__ offs, int* __restrict__ esrc) {
    __shared__ int sm[256];
    const int t = threadIdx.x, b = blockIdx.x;
    int part = 0;
    for (int i = t; i < b; i += 256) part += blksum[i];
    sm[t] = part;
    __syncthreads();
    for (int d = 128; d > 0; d >>= 1) {
        if (t < d) sm[t] += sm[t + d];
        __syncthreads();
    }
    const int boff = sm[0];
    int i = b * 256 + t;
    if (i < NNODES) {
        int o1 = incl[i] + boff;
        offs[i + 1] = o1;
        esrc[o1 - (cnt[i] + 1)] = i;   // slot 0 of node i's bucket = self edge
    }
    if (i == 0) offs[0] = 0;
}

// ---------------- per-bucket exact scatter (L2-local, block-exclusive region) ----------------
__global__ __launch_bounds__(256) void k_fill2(const int* __restrict__ gbcnt,
        const int* __restrict__ bsrc, const unsigned char* __restrict__ bdst8,
        const int* __restrict__ offs, int* __restrict__ esrc) {
    __shared__ int loff[256], lcur[256];
    const int t = threadIdx.x, b = blockIdx.x;
    int node = b * 256 + t;
    loff[t] = (node < NNODES) ? offs[node] : 0;
    lcur[t] = 0;
    __syncthreads();
    const int ne = min(gbcnt[b], BCAP);
    const int* bs = bsrc + (size_t)b * BCAP;
    const unsigned char* bd = bdst8 + (size_t)b * BCAP;
    for (int i = t; i < ne; i += 256) {
        int s = bs[i];
        int li = bd[i];
        int p = loff[li] + 1 + atomicAdd(&lcur[li], 1);   // +1: slot 0 is self-loop
        esrc[p] = s;
    }
}

// ---------------- MFMA fp16 GEMM, single-pass A: BM=64, BN=256, BK=64, 4 waves ----------------
template<bool A32>
__global__ __launch_bounds__(256) void gemm_w(const void* __restrict__ Ap,
        const unsigned short* __restrict__ BT, unsigned short* __restrict__ C,
        const float* __restrict__ dinv) {
    __shared__ __align__(16) char lds[81920];   // 2 bufs x (A 8K + B 32K)
    const int t = threadIdx.x;
    const int w = t >> 6, l = t & 63;
    const int bm = blockIdx.x * 64;
    const int lr = l >> 3, ls = l & 7;
    const unsigned short* A16 = (const unsigned short*)Ap;
    const float* A32p = (const float*)Ap;

    auto stageB = [&](int buf, int k0) {
        char* base = lds + buf * 40960 + 8192;
#pragma unroll
        for (int i = 0; i < 8; ++i) {
            int r = w * 64 + i * 8 + lr;
            int sl = ls ^ (r & 7);
            const char* gB = (const char*)BT + (size_t)r * 512 + (size_t)k0 * 2 + sl * 16;
            gload_lds16(gB, base + (w * 64 + i * 8) * 128);
        }
    };
    auto stageA16 = [&](int buf, int k0) {
        char* base = lds + buf * 40960;
#pragma unroll
        for (int i = 0; i < 2; ++i) {
            int r = w * 16 + i * 8 + lr;
            int sl = ls ^ (r & 7);
            const char* gA = (const char*)A16 + (size_t)(bm + r) * 512 + (size_t)k0 * 2 + sl * 16;
            gload_lds16(gA, base + (w * 16 + i * 8) * 128);
        }
    };
    float4 areg[4];
    const int arow = t >> 2, akq = (t & 3) << 4;
    auto issueA32 = [&](int k0) {
#pragma unroll
        for (int i = 0; i < 4; ++i) {
            float4 v = make_float4(0.f, 0.f, 0.f, 0.f);
            if (bm + arow < NNODES) v = *(const float4*)(A32p + (size_t)(bm + arow) * 256 + k0 + akq + i * 4);
            areg[i] = v;
        }
    };
    auto writeA32 = [&](int buf) {
        char* base = lds + buf * 40960;
        f16 h[16];
#pragma unroll
        for (int i = 0; i < 4; ++i) {
            h[i * 4 + 0] = (f16)areg[i].x; h[i * 4 + 1] = (f16)areg[i].y;
            h[i * 4 + 2] = (f16)areg[i].z; h[i * 4 + 3] = (f16)areg[i].w;
        }
        int s0 = (t & 3) * 2;
        char* d0 = base + arow * 128 + ((s0 ^ (arow & 7)) * 16);
        char* d1 = base + arow * 128 + (((s0 + 1) ^ (arow & 7)) * 16);
        __builtin_memcpy(d0, &h[0], 16);
        __builtin_memcpy(d1, &h[8], 16);
    };

    f32x4 acc[4][4];
#pragma unroll
    for (int m = 0; m < 4; ++m)
#pragma unroll
        for (int n = 0; n < 4; ++n)
            acc[m][n] = (f32x4){0.f, 0.f, 0.f, 0.f};

    const int frow = l & 15, fk = l >> 4;

    if constexpr (A32) { issueA32(0); } else { stageA16(0, 0); }
    stageB(0, 0);
    if constexpr (A32) { writeA32(0); }
    __syncthreads();
    for (int kt = 0; kt < 4; ++kt) {
        const int buf = kt & 1;
        if (kt < 3) {
            if constexpr (A32) { issueA32((kt + 1) * 64); } else { stageA16(buf ^ 1, (kt + 1) * 64); }
            stageB(buf ^ 1, (kt + 1) * 64);
        }
        const char* As = lds + buf * 40960;
        const char* Bs = As + 8192;
#pragma unroll
        for (int ks = 0; ks < 2; ++ks) {
            f16x8 af[4], bf[4];
#pragma unroll
            for (int m = 0; m < 4; ++m) {
                int ra = m * 16 + frow;
                af[m] = *(const f16x8*)(As + ra * 128 + (((ks * 4 + fk) ^ (ra & 7)) * 16));
            }
#pragma unroll
            for (int n = 0; n < 4; ++n) {
                int rb = w * 64 + n * 16 + frow;
                bf[n] = *(const f16x8*)(Bs + rb * 128 + (((ks * 4 + fk) ^ (rb & 7)) * 16));
            }
#pragma unroll
            for (int m = 0; m < 4; ++m)
#pragma unroll
                for (int n = 0; n < 4; ++n)
                    acc[m][n] = __builtin_amdgcn_mfma_f32_16x16x32_f16(af[m], bf[n], acc[m][n], 0, 0, 0);
        }
        if constexpr (A32) { if (kt < 3) writeA32(buf ^ 1); }
        __syncthreads();
    }

    unsigned short* Cs = (unsigned short*)lds;   // [64][264]
    const int crow = (l >> 4) * 4, ccol = l & 15;
#pragma unroll
    for (int m = 0; m < 4; ++m) {
        float4 dv = *(const float4*)(dinv + bm + m * 16 + crow);
        float d4[4] = {dv.x, dv.y, dv.z, dv.w};
#pragma unroll
        for (int n = 0; n < 4; ++n)
#pragma unroll
            for (int r = 0; r < 4; ++r)
                Cs[(m * 16 + crow + r) * 264 + w * 64 + n * 16 + ccol] = f2h(acc[m][n][r] * d4[r]);
    }
    __syncthreads();
#pragma unroll
    for (int i = 0; i < 8; ++i) {
        int idx = i * 256 + t;
        int row = idx >> 5, cs = idx & 31;
        uint4 v = *(const uint4*)(Cs + row * 264 + cs * 8);
        *(uint4*)((char*)C + (size_t)(bm + row) * 512 + cs * 16) = v;
    }
}

// ---------------- layer-3 MFMA GEMM (proven 128x128 kernel, narrow C-write) ----------------
__global__ __launch_bounds__(256) void gemm_n(const unsigned short* __restrict__ A16,
        const unsigned short* __restrict__ BT, unsigned short* __restrict__ C,
        const float* __restrict__ dinv) {
    __shared__ __align__(16) char lds[65536];
    const int t = threadIdx.x;
    const int w = t >> 6, l = t & 63;
    const int bm = blockIdx.x * 128;
    const int lr = l >> 3, ls = l & 7;

    auto stage = [&](int buf, int k0) {
        char* base = lds + buf * 32768;
#pragma unroll
        for (int i = 0; i < 4; ++i) {
            int r = w * 32 + i * 8 + lr;
            int sl = ls ^ (r & 7);
            const char* gA = (const char*)A16 + (size_t)(bm + r) * 512 + (size_t)k0 * 2 + sl * 16;
            gload_lds16(gA, base + (w * 32 + i * 8) * 128);
            const char* gB = (const char*)BT + (size_t)r * 512 + (size_t)k0 * 2 + sl * 16;
            gload_lds16(gB, base + 16384 + (w * 32 + i * 8) * 128);
        }
    };

    f32x4 acc[4][4];
#pragma unroll
    for (int m = 0; m < 4; ++m)
#pragma unroll
        for (int n = 0; n < 4; ++n)
            acc[m][n] = (f32x4){0.f, 0.f, 0.f, 0.f};

    const int frow = l & 15, fk = l >> 4;
    const int r0w = (w >> 1) * 64, c0w = (w & 1) * 64;

    stage(0, 0);
    __syncthreads();
    for (int kt = 0; kt < 4; ++kt) {
        const int buf = kt & 1;
        if (kt < 3) stage(buf ^ 1, (kt + 1) * 64);
        const char* As = lds + buf * 32768;
        const char* Bs = As + 16384;
#pragma unroll
        for (int ks = 0; ks < 2; ++ks) {
            f16x8 af[4], bf[4];
#pragma unroll
            for (int m = 0; m < 4; ++m) {
                int ra = r0w + m * 16 + frow;
                af[m] = *(const f16x8*)(As + ra * 128 + (((ks * 4 + fk) ^ (ra & 7)) * 16));
            }
#pragma unroll
            for (int n = 0; n < 4; ++n) {
                int rb = c0w + n * 16 + frow;
                bf[n] = *(const f16x8*)(Bs + rb * 128 + (((ks * 4 + fk) ^ (rb & 7)) * 16));
            }
#pragma unroll
            for (int m = 0; m < 4; ++m)
#pragma unroll
                for (int n = 0; n < 4; ++n)
                    acc[m][n] = __builtin_amdgcn_mfma_f32_16x16x32_f16(af[m], bf[n], acc[m][n], 0, 0, 0);
        }
        __syncthreads();
    }

    unsigned short* Cs = (unsigned short*)lds;   // [128][136]
    const int crow = (l >> 4) * 4, ccol = l & 15;
#pragma unroll
    for (int m = 0; m < 4; ++m) {
        float4 dv = *(const float4*)(dinv + bm + r0w + m * 16 + crow);
        float d4[4] = {dv.x, dv.y, dv.z, dv.w};
#pragma unroll
        for (int n = 0; n < 4; ++n)
#pragma unroll
            for (int r = 0; r < 4; ++r)
                Cs[(r0w + m * 16 + crow + r) * 136 + c0w + n * 16 + ccol] = f2h(acc[m][n][r] * d4[r]);
    }
    __syncthreads();
#pragma unroll
    for (int i = 0; i < 8; ++i) {
        int row = i * 16 + (t >> 4);
        int cs = t & 15;
        if (cs < 5) {
            uint4 v = *(const uint4*)(Cs + row * 136 + cs * 8);
            *(uint4*)((char*)C + (size_t)(bm + row) * 80 + cs * 16) = v;
        }
    }
}

// ---------------- aggregation v3 (proven): register-cached indices, readlane addr, fma_mix ----------------
__global__ __launch_bounds__(256) void agg_v3(const unsigned short* __restrict__ T,
        const int* __restrict__ esrc, const int* __restrict__ offs,
        const float* __restrict__ dinv, const float* __restrict__ bias,
        unsigned short* __restrict__ outh) {
    int node = blockIdx.x * 4 + (threadIdx.x >> 6);
    if (node >= NNODES) return;
    const int l = threadIdx.x & 63;
    const float one = 1.0f;
    const int e0 = offs[node], e1 = offs[node + 1];
    const int ne = e1 - e0;
    const int myidx = esrc[e0 + min(l, ne - 1)];   // cache up to 64 indices, one per lane
    const char* Tb = (const char*)T;
    float a0 = 0.f, a1 = 0.f, a2 = 0.f, a3 = 0.f;
    const int nreg = min(ne, 64);
    int j = 0;
    for (; j + 8 <= nreg; j += 8) {
        uint2 u[8];
#pragma unroll
        for (int q = 0; q < 8; ++q) {
            int s = __builtin_amdgcn_readlane(myidx, j + q);
            u[q] = *(const uint2*)(Tb + (size_t)s * 512 + l * 8);
        }
#pragma unroll
        for (int q = 0; q < 8; ++q) {
            fmix2(a0, a1, u[q].x, one);
            fmix2(a2, a3, u[q].y, one);
        }
    }
    for (; j < nreg; ++j) {
        int s = __builtin_amdgcn_readlane(myidx, j);
        uint2 u = *(const uint2*)(Tb + (size_t)s * 512 + l * 8);
        fmix2(a0, a1, u.x, one);
        fmix2(a2, a3, u.y, one);
    }
    for (int e = e0 + 64; e < e1; ++e) {   // deg > 63 fallback
        int s = esrc[e];
        uint2 u = *(const uint2*)(Tb + (size_t)s * 512 + l * 8);
        fmix2(a0, a1, u.x, one);
        fmix2(a2, a3, u.y, one);
    }
    float di = dinv[node];
    float4 bv = *(const float4*)(bias + l * 4);
    float r0 = fmaxf(fmaf(a0, di, bv.x), 0.f);
    float r1 = fmaxf(fmaf(a1, di, bv.y), 0.f);
    float r2 = fmaxf(fmaf(a2, di, bv.z), 0.f);
    float r3 = fmaxf(fmaf(a3, di, bv.w), 0.f);
    uint2 o;
    o.x = (unsigned)f2h(r0) | ((unsigned)f2h(r1) << 16);
    o.y = (unsigned)f2h(r2) | ((unsigned)f2h(r3) << 16);
    *(uint2*)(outh + (size_t)node * 256 + l * 4) = o;
}

// ---------------- layer-3 aggregation: register indices + fma_mix; 16-lane group per edge ----------------
__global__ __launch_bounds__(256) void agg_out_v3(const unsigned short* __restrict__ T,
        const int* __restrict__ esrc, const int* __restrict__ offs,
        const float* __restrict__ dinv, const float* __restrict__ bias,
        float* __restrict__ out) {
    int node = blockIdx.x * 4 + (threadIdx.x >> 6);
    if (node >= NNODES) return;
    const int l = threadIdx.x & 63;
    const int g = l >> 4, sl = l & 15;
    const bool act = sl < 10;
    const float one = 1.0f;
    const int e0 = offs[node], e1 = offs[node + 1];
    const int ne = e1 - e0;
    const int myidx = esrc[e0 + min(l, ne - 1)];
    const int nreg = min(ne, 64);
    const char* Tb = (const char*)T;
    float a0 = 0.f, a1 = 0.f, a2 = 0.f, a3 = 0.f;
    for (int j = 0; j < nreg; j += 4) {
        int jj = j + g;
        int s = __shfl(myidx, min(jj, 63), 64);
        if (jj < nreg && act) {
            uint2 u = *(const uint2*)(Tb + (size_t)s * 80 + sl * 8);
            fmix2(a0, a1, u.x, one);
            fmix2(a2, a3, u.y, one);
        }
    }
    for (int e = e0 + 64 + g; e < e1; e += 4) {   // deg > 63 fallback
        int s = esrc[e];
        if (act) {
            uint2 u = *(const uint2*)(Tb + (size_t)s * 80 + sl * 8);
            fmix2(a0, a1, u.x, one);
            fmix2(a2, a3, u.y, one);
        }
    }
    a0 += __shfl_xor(a0, 16, 64); a1 += __shfl_xor(a1, 16, 64);
    a2 += __shfl_xor(a2, 16, 64); a3 += __shfl_xor(a3, 16, 64);
    a0 += __shfl_xor(a0, 32, 64); a1 += __shfl_xor(a1, 32, 64);
    a2 += __shfl_xor(a2, 32, 64); a3 += __shfl_xor(a3, 32, 64);
    if (g == 0 && act) {
        float di = dinv[node];
        float4 bv = *(const float4*)(bias + sl * 4);
        float4 o = make_float4(fmaf(a0, di, bv.x), fmaf(a1, di, bv.y),
                               fmaf(a2, di, bv.z), fmaf(a3, di, bv.w));
        *(float4*)(out + (size_t)node * 40 + sl * 4) = o;
    }
}

extern "C" void kernel_launch(void* const* d_in, const int* in_sizes, int n_in,
                              void* d_out, int out_size, void* d_ws, size_t ws_size,
                              hipStream_t stream) {
    const float* x  = (const float*)d_in[0];
    const int*   ei = (const int*)d_in[1];
    const float* W1 = (const float*)d_in[2];
    const float* b1 = (const float*)d_in[3];
    const float* W2 = (const float*)d_in[4];
    const float* b2 = (const float*)d_in[5];
    const float* W3 = (const float*)d_in[6];
    const float* b3 = (const float*)d_in[7];
    float* out = (float*)d_out;

    char* ws = (char*)d_ws;
    size_t o = 0;
    unsigned short* tbA  = (unsigned short*)(ws + o); o += (size_t)MPAD * 256 * 2;   // gemm out (dinv-scaled)
    unsigned short* tbB  = (unsigned short*)(ws + o); o += (size_t)MPAD * 256 * 2;   // agg out (h, relu'd)
    unsigned short* tb40 = (unsigned short*)(ws + o); o += (size_t)MPAD * NCLS * 2;  // layer-3 table
    unsigned short* W1T  = (unsigned short*)(ws + o); o += 131072;
    unsigned short* W2T  = (unsigned short*)(ws + o); o += 131072;
    unsigned short* W3T  = (unsigned short*)(ws + o); o += 65536;    // [128][256] padded
    int* bsrc    = (int*)(ws + o);   o += (size_t)NBUCK * BCAP * 4;  // 8 MB
    unsigned char* bdst8 = (unsigned char*)(ws + o); o += (size_t)NBUCK * BCAP + 256;
    int* gbcnt   = (int*)(ws + o);   o += 2048;
    int* esrc    = (int*)(ws + o);   o += (size_t)(NEDGES + NNODES) * 4;
    int* cnt     = (int*)(ws + o);   o += 400128;
    int* offs    = (int*)(ws + o);   o += 400384;
    float* dinv  = (float*)(ws + o); o += 400384;   // MPAD entries, pad=0
    int* incl    = (int*)(ws + o);   o += 400128;
    int* blksum  = (int*)(ws + o);   o += 2048;
    int* flag    = (int*)(ws + o);   o += 256;
    if (ws_size < o) return;

    k_wts<<<641, 256, 0, stream>>>(W1, W2, W3, W1T, W2T, W3T,
                                   tbB + (size_t)NNODES * 256, ei, flag, gbcnt);
    k_bucket<<<NBLKB, 256, 0, stream>>>(ei, flag, gbcnt, bsrc, bdst8);
    k_cntscan<<<NBLK_SCAN, 256, 0, stream>>>(gbcnt, bdst8, cnt, dinv, incl, blksum);
    k_scan23<<<NBLK_SCAN, 256, 0, stream>>>(blksum, incl, cnt, offs, esrc);
    k_fill2<<<NBUCK, 256, 0, stream>>>(gbcnt, bsrc, bdst8, offs, esrc);

    dim3 b256(256);
    // layer 1 (A = fp32 x, read once)
    gemm_w<true><<<MPAD / 64, b256, 0, stream>>>(x, W1T, tbA, dinv);
    agg_v3<<<NNODES / 4, 256, 0, stream>>>(tbA, esrc, offs, dinv, b1, tbB);
    // layer 2
    gemm_w<false><<<MPAD / 64, b256, 0, stream>>>(tbB, W2T, tbA, dinv);
    agg_v3<<<NNODES / 4, 256, 0, stream>>>(tbA, esrc, offs, dinv, b2, tbB);
    // layer 3 (proven 128x128 kernel, narrow C-write)
    gemm_n<<<MPAD / 128, b256, 0, stream>>>(tbB, W3T, tb40, dinv);
    agg_out_v3<<<NNODES / 4, 256, 0, stream>>>(tb40, esrc, offs, dinv, b3, out);
}